// Round 1
// baseline (821.522 us; speedup 1.0000x reference)
//
#include <hip/hip_runtime.h>
#include <math.h>

#define NTOK 8192
#define SD   4096
#define ITERS 20

// ---------------- Kernel A: l2 norm + code = s_norm @ compress ----------------
// 16 tokens per block, 256 threads. Wave w handles i in [w*1024, w*1024+1024) for all 16 tokens.
__global__ __launch_bounds__(256) void k_code(const float* __restrict__ s,
                                              const float* __restrict__ gamma,
                                              const float* __restrict__ compress,
                                              float* __restrict__ code)
{
    __shared__ float wred[64];
    __shared__ float scale_sh[16];
    __shared__ float part[4 * 16 * 64];
    const int tid  = threadIdx.x;
    const int lane = tid & 63;
    const int wid  = tid >> 6;
    const int tok0 = blockIdx.x * 16;

    // phase 1: sum of squares per token
    for (int tk = 0; tk < 16; ++tk) {
        const float4* sp4 = (const float4*)(s + (size_t)(tok0 + tk) * SD);
        float ss = 0.f;
        #pragma unroll
        for (int j = 0; j < 4; ++j) {
            float4 x = sp4[j * 256 + tid];
            ss += x.x * x.x + x.y * x.y + x.z * x.z + x.w * x.w;
        }
        #pragma unroll
        for (int m = 1; m < 64; m <<= 1) ss += __shfl_xor(ss, m);
        if (lane == 0) wred[tk * 4 + wid] = ss;
    }
    __syncthreads();
    if (tid < 16) {
        float l2 = sqrtf(wred[tid * 4 + 0] + wred[tid * 4 + 1] + wred[tid * 4 + 2] + wred[tid * 4 + 3]);
        scale_sh[tid] = 64.0f / fmaxf(l2, 1e-12f);
    }
    __syncthreads();

    // phase 2: code[tok][d] = scale[tok] * sum_i s[tok][i]*(gamma[i]+1)*compress[i][d]
    float acc[16];
    #pragma unroll
    for (int tk = 0; tk < 16; ++tk) acc[tk] = 0.f;
    const int d  = lane;
    const int i0 = wid * 1024;
    #pragma unroll 4
    for (int ii = 0; ii < 1024; ++ii) {
        const int i = i0 + ii;
        const float cg = compress[(size_t)i * 64 + d] * (gamma[i] + 1.0f);
        #pragma unroll
        for (int tk = 0; tk < 16; ++tk)
            acc[tk] += s[(size_t)(tok0 + tk) * SD + i] * cg;
    }
    #pragma unroll
    for (int tk = 0; tk < 16; ++tk) part[wid * 1024 + tk * 64 + d] = acc[tk];
    __syncthreads();

    const int d2 = tid & 63, grp = tid >> 6;
    #pragma unroll
    for (int tt = 0; tt < 4; ++tt) {
        const int tk = grp * 4 + tt;
        float v = part[0 * 1024 + tk * 64 + d2] + part[1 * 1024 + tk * 64 + d2] +
                  part[2 * 1024 + tk * 64 + d2] + part[3 * 1024 + tk * 64 + d2];
        code[(size_t)(tok0 + tk) * 64 + d2] = v * scale_sh[tk];
    }
}

// ---------------- wave-parallel log-domain Sinkhorn ----------------
// Element e = j*64 + lane maps to (r, c) = (e / COLS, e % COLS), row-major.
// Row-lse: shfl_xor masks < COLS. Col-lse: in-lane over j, then masks >= COLS.
template <int ROWS, int COLS, int J>
__device__ inline void wave_sinkhorn(const float* Z, float* P)
{
    const float lr = -logf((float)ROWS);
    const float lc = -logf((float)COLS);
    float u[J], v[J];
    #pragma unroll
    for (int j = 0; j < J; ++j) { u[j] = 0.f; v[j] = 0.f; }

    for (int it = 0; it < ITERS; ++it) {
        // u = lr - lse_cols(Z + v)
        float t[J], m[J], sm[J];
        #pragma unroll
        for (int j = 0; j < J; ++j) { t[j] = Z[j] + v[j]; m[j] = t[j]; }
        #pragma unroll
        for (int mask = 1; mask < COLS; mask <<= 1)
            #pragma unroll
            for (int j = 0; j < J; ++j) m[j] = fmaxf(m[j], __shfl_xor(m[j], mask));
        #pragma unroll
        for (int j = 0; j < J; ++j) sm[j] = expf(t[j] - m[j]);
        #pragma unroll
        for (int mask = 1; mask < COLS; mask <<= 1)
            #pragma unroll
            for (int j = 0; j < J; ++j) sm[j] += __shfl_xor(sm[j], mask);
        #pragma unroll
        for (int j = 0; j < J; ++j) u[j] = lr - (m[j] + logf(sm[j]));

        // v = lc - lse_rows(Z + u)
        #pragma unroll
        for (int j = 0; j < J; ++j) t[j] = Z[j] + u[j];
        float mm = t[0];
        #pragma unroll
        for (int j = 1; j < J; ++j) mm = fmaxf(mm, t[j]);
        #pragma unroll
        for (int mask = COLS; mask < 64; mask <<= 1) mm = fmaxf(mm, __shfl_xor(mm, mask));
        float ss = 0.f;
        #pragma unroll
        for (int j = 0; j < J; ++j) ss += expf(t[j] - mm);
        #pragma unroll
        for (int mask = COLS; mask < 64; mask <<= 1) ss += __shfl_xor(ss, mask);
        const float vv = lc - (mm + logf(ss));
        #pragma unroll
        for (int j = 0; j < J; ++j) v[j] = vv;
    }
    #pragma unroll
    for (int j = 0; j < J; ++j) P[j] = expf(Z[j] + u[j] + v[j]) * (float)ROWS;
}

// ---------------- Kernel B: logits -> 4 sinkhorns -> P_na/P_np + layer_in ----------------
__global__ __launch_bounds__(256) void k_route(const float* __restrict__ s,
                                               const float* __restrict__ code,
                                               const float* __restrict__ a_pre_p, const float* __restrict__ tl_pre, const float* __restrict__ H_pre,
                                               const float* __restrict__ a_al_p,  const float* __restrict__ tl_al,  const float* __restrict__ H_al,
                                               const float* __restrict__ a_nx_p,  const float* __restrict__ tl_nx,  const float* __restrict__ H_nx,
                                               const float* __restrict__ a_po_p,  const float* __restrict__ tl_po,  const float* __restrict__ H_po,
                                               float* __restrict__ layer_in,
                                               float* __restrict__ Pna, float* __restrict__ Pnp)
{
    __shared__ float code_sh[64];
    __shared__ float s_sh[SD];
    __shared__ float Ppre_sh[64], Pal_sh[256], Pnx_sh[256], Ppo_sh[64];
    const int tid  = threadIdx.x;
    const int lane = tid & 63;
    const int wid  = tid >> 6;
    const int tok  = blockIdx.x;

    if (tid < 64) code_sh[tid] = code[(size_t)tok * 64 + tid];
    {
        const float4* sp4 = (const float4*)(s + (size_t)tok * SD);
        float4* d4 = (float4*)s_sh;
        #pragma unroll
        for (int j = 0; j < 4; ++j) d4[j * 256 + tid] = sp4[j * 256 + tid];
    }
    __syncthreads();

    if (wid == 0) {            // pre: 4 x 16
        float raw = 0.f;
        for (int dd = 0; dd < 64; ++dd) raw += code_sh[dd] * tl_pre[dd * 64 + lane];
        float Z[1], P[1];
        Z[0] = (*a_pre_p) * raw + H_pre[lane];
        wave_sinkhorn<4, 16, 1>(Z, P);
        Ppre_sh[lane] = P[0];
    } else if (wid == 1) {     // align: 16 x 16
        float raw[4] = {0.f, 0.f, 0.f, 0.f};
        for (int dd = 0; dd < 64; ++dd) {
            const float cdv = code_sh[dd];
            #pragma unroll
            for (int j = 0; j < 4; ++j) raw[j] += cdv * tl_al[dd * 256 + j * 64 + lane];
        }
        const float aa = *a_al_p;
        float Z[4], P[4];
        #pragma unroll
        for (int j = 0; j < 4; ++j) Z[j] = aa * raw[j] + H_al[j * 64 + lane];
        wave_sinkhorn<16, 16, 4>(Z, P);
        #pragma unroll
        for (int j = 0; j < 4; ++j) Pal_sh[j * 64 + lane] = P[j];
    } else if (wid == 2) {     // next: 16 x 16
        float raw[4] = {0.f, 0.f, 0.f, 0.f};
        for (int dd = 0; dd < 64; ++dd) {
            const float cdv = code_sh[dd];
            #pragma unroll
            for (int j = 0; j < 4; ++j) raw[j] += cdv * tl_nx[dd * 256 + j * 64 + lane];
        }
        const float aa = *a_nx_p;
        float Z[4], P[4];
        #pragma unroll
        for (int j = 0; j < 4; ++j) Z[j] = aa * raw[j] + H_nx[j * 64 + lane];
        wave_sinkhorn<16, 16, 4>(Z, P);
        #pragma unroll
        for (int j = 0; j < 4; ++j) Pnx_sh[j * 64 + lane] = P[j];
    } else {                   // post: 16 x 4
        float raw = 0.f;
        for (int dd = 0; dd < 64; ++dd) raw += code_sh[dd] * tl_po[dd * 64 + lane];
        float Z[1], P[1];
        Z[0] = (*a_po_p) * raw + H_po[lane];
        wave_sinkhorn<16, 4, 1>(Z, P);
        Ppo_sh[lane] = P[0];
    }
    __syncthreads();

    // P_na = P_next @ P_align (16x16), P_np = P_next @ P_post (16x4)
    {
        const int m = tid >> 4, jj = tid & 15;
        float acc = 0.f;
        #pragma unroll
        for (int t2 = 0; t2 < 16; ++t2) acc += Pnx_sh[m * 16 + t2] * Pal_sh[t2 * 16 + jj];
        Pna[(size_t)tok * 256 + tid] = acc;
    }
    if (tid < 64) {
        const int m = tid >> 2, q = tid & 3;
        float acc = 0.f;
        #pragma unroll
        for (int t2 = 0; t2 < 16; ++t2) acc += Pnx_sh[m * 16 + t2] * Ppo_sh[t2 * 4 + q];
        Pnp[(size_t)tok * 64 + tid] = acc;
    }
    // layer_in[i*256+c] = sum_j Ppre[i][j] * s[j*256+c]
    {
        const int c = tid;
        #pragma unroll
        for (int i = 0; i < 4; ++i) {
            float acc = 0.f;
            #pragma unroll
            for (int j = 0; j < 16; ++j) acc += Ppre_sh[i * 16 + j] * s_sh[j * 256 + c];
            layer_in[(size_t)tok * 1024 + i * 256 + c] = acc;
        }
    }
}

// ---------------- Kernel C: layer_out = layer_in @ W  (8192x1024x1024, f32) ----------------
__global__ __launch_bounds__(256) void k_gemm(const float* __restrict__ A,
                                              const float* __restrict__ B,
                                              float* __restrict__ C)
{
    __shared__ float As[16][68];
    __shared__ float Bs[16][68];
    const int tid = threadIdx.x;
    const int tx = tid & 15, ty = tid >> 4;
    const int row0 = blockIdx.y * 64, col0 = blockIdx.x * 64;
    float acc[4][4];
    #pragma unroll
    for (int i = 0; i < 4; ++i)
        #pragma unroll
        for (int j = 0; j < 4; ++j) acc[i][j] = 0.f;

    for (int k0 = 0; k0 < 1024; k0 += 16) {
        {
            const int r = tid >> 2, kq = tid & 3;
            const float4 a4 = *(const float4*)(A + (size_t)(row0 + r) * 1024 + k0 + kq * 4);
            As[kq * 4 + 0][r] = a4.x; As[kq * 4 + 1][r] = a4.y;
            As[kq * 4 + 2][r] = a4.z; As[kq * 4 + 3][r] = a4.w;
            const int kk = tid >> 4, c4 = (tid & 15) * 4;
            *(float4*)&Bs[kk][c4] = *(const float4*)(B + (size_t)(k0 + kk) * 1024 + col0 + c4);
        }
        __syncthreads();
        #pragma unroll
        for (int kk = 0; kk < 16; ++kk) {
            float a[4], b[4];
            *(float4*)a = *(const float4*)&As[kk][ty * 4];
            *(float4*)b = *(const float4*)&Bs[kk][tx * 4];
            #pragma unroll
            for (int i = 0; i < 4; ++i)
                #pragma unroll
                for (int j = 0; j < 4; ++j) acc[i][j] += a[i] * b[j];
        }
        __syncthreads();
    }
    #pragma unroll
    for (int i = 0; i < 4; ++i) {
        float4 o; o.x = acc[i][0]; o.y = acc[i][1]; o.z = acc[i][2]; o.w = acc[i][3];
        *(float4*)&C[(size_t)(row0 + ty * 4 + i) * 1024 + col0 + tx * 4] = o;
    }
}

// ---------------- Kernel D: s_next = P_na @ s + P_np @ layer_out ----------------
__global__ __launch_bounds__(256) void k_final(const float* __restrict__ s,
                                               const float* __restrict__ lo,
                                               const float* __restrict__ Pna,
                                               const float* __restrict__ Pnp,
                                               float* __restrict__ out)
{
    __shared__ float s_sh[SD];
    __shared__ float lo_sh[1024];
    __shared__ float Pna_sh[256];
    __shared__ float Pnp_sh[64];
    const int tid = threadIdx.x;
    const int tok = blockIdx.x;

    {
        const float4* sp4 = (const float4*)(s + (size_t)tok * SD);
        float4* d4 = (float4*)s_sh;
        #pragma unroll
        for (int j = 0; j < 4; ++j) d4[j * 256 + tid] = sp4[j * 256 + tid];
        ((float4*)lo_sh)[tid] = ((const float4*)(lo + (size_t)tok * 1024))[tid];
        Pna_sh[tid] = Pna[(size_t)tok * 256 + tid];
        if (tid < 64) Pnp_sh[tid] = Pnp[(size_t)tok * 64 + tid];
    }
    __syncthreads();

    const int c = tid;
    #pragma unroll
    for (int m = 0; m < 16; ++m) {
        float acc = 0.f;
        #pragma unroll
        for (int j = 0; j < 16; ++j) acc += Pna_sh[m * 16 + j] * s_sh[j * 256 + c];
        #pragma unroll
        for (int q = 0; q < 4; ++q) acc += Pnp_sh[m * 4 + q] * lo_sh[q * 256 + c];
        out[(size_t)tok * SD + m * 256 + c] = acc;
    }
}

extern "C" void kernel_launch(void* const* d_in, const int* in_sizes, int n_in,
                              void* d_out, int out_size, void* d_ws, size_t ws_size,
                              hipStream_t stream)
{
    const float* s        = (const float*)d_in[0];
    const float* gamma    = (const float*)d_in[1];
    const float* compress = (const float*)d_in[2];
    const float* a_pre    = (const float*)d_in[3];
    const float* tl_pre   = (const float*)d_in[4];
    const float* H_pre    = (const float*)d_in[5];
    const float* a_al     = (const float*)d_in[6];
    const float* tl_al    = (const float*)d_in[7];
    const float* H_al     = (const float*)d_in[8];
    const float* a_nx     = (const float*)d_in[9];
    const float* tl_nx    = (const float*)d_in[10];
    const float* H_nx     = (const float*)d_in[11];
    const float* a_po     = (const float*)d_in[12];
    const float* tl_po    = (const float*)d_in[13];
    const float* H_po     = (const float*)d_in[14];
    const float* W        = (const float*)d_in[15];
    float* out = (float*)d_out;

    float* code      = (float*)d_ws;                     // 8192*64
    float* layer_in  = code      + (size_t)8192 * 64;    // 8192*1024
    float* layer_out = layer_in  + (size_t)8192 * 1024;  // 8192*1024
    float* Pna       = layer_out + (size_t)8192 * 1024;  // 8192*256
    float* Pnp       = Pna       + (size_t)8192 * 256;   // 8192*64

    k_code<<<512, 256, 0, stream>>>(s, gamma, compress, code);
    k_route<<<NTOK, 256, 0, stream>>>(s, code,
                                      a_pre, tl_pre, H_pre,
                                      a_al,  tl_al,  H_al,
                                      a_nx,  tl_nx,  H_nx,
                                      a_po,  tl_po,  H_po,
                                      layer_in, Pna, Pnp);
    k_gemm<<<dim3(16, 128), 256, 0, stream>>>(layer_in, W, layer_out);
    k_final<<<NTOK, 256, 0, stream>>>(s, layer_out, Pna, Pnp, out);
}

// Round 2
// 515.740 us; speedup vs baseline: 1.5929x; 1.5929x over previous
//
#include <hip/hip_runtime.h>
#include <math.h>

#define NTOK 8192
#define SD   4096
#define ITERS 20

typedef __attribute__((ext_vector_type(8))) short short8;
typedef __attribute__((ext_vector_type(4))) float f32x4;

__device__ inline unsigned short f2bf(float x) {
    unsigned int u = __float_as_uint(x);
    unsigned int r = (u + 0x7FFFu + ((u >> 16) & 1u)) >> 16;
    return (unsigned short)r;
}

// ---------------- Kernel A: fused l2-norm + code = s_norm @ compress ----------------
// 16 tokens/block, 256 threads. s staged through LDS in 512-wide tiles; ssq fused into staging.
__global__ __launch_bounds__(256) void k_code2(const float* __restrict__ s,
                                               const float* __restrict__ gamma,
                                               const float* __restrict__ compress,
                                               float* __restrict__ code)
{
    __shared__ float s_sh[16 * 512];     // [tk][512]
    __shared__ float part[4 * 16 * 64];  // [wid][tk][d]
    __shared__ float scale_sh[16];
    const int tid  = threadIdx.x;
    const int lane = tid & 63;
    const int wid  = tid >> 6;
    const int tok0 = blockIdx.x * 16;
    const int my_tk = tid >> 4;   // staging token for this thread
    const int f0    = tid & 15;   // float4 slot base

    float ssq = 0.f;
    float acc[16];
    #pragma unroll
    for (int tk = 0; tk < 16; ++tk) acc[tk] = 0.f;
    const int d = lane;

    for (int t = 0; t < 8; ++t) {
        __syncthreads();  // WAR: previous tile's readers done
        // stage: 8 float4/thread, all from token my_tk (coalesced 256B chunks)
        const float4* srcp = (const float4*)(s + (size_t)(tok0 + my_tk) * SD + t * 512);
        float4* dstp = (float4*)(s_sh + my_tk * 512);
        #pragma unroll
        for (int q = 0; q < 8; ++q) {
            const int f = q * 16 + f0;
            float4 v = srcp[f];
            dstp[f] = v;
            ssq += v.x * v.x + v.y * v.y + v.z * v.z + v.w * v.w;
        }
        __syncthreads();
        // GEMV from LDS: wave wid covers ii in [wid*128, wid*128+128) of this tile
        const int i0 = t * 512 + wid * 128;
        #pragma unroll 2
        for (int c = 0; c < 128; c += 4) {
            const int ig = i0 + c;
            float cg[4];
            #pragma unroll
            for (int jj = 0; jj < 4; ++jj)
                cg[jj] = compress[(size_t)(ig + jj) * 64 + d] * (gamma[ig + jj] + 1.0f);
            #pragma unroll
            for (int tk = 0; tk < 16; ++tk) {
                float4 sv = *(const float4*)(s_sh + tk * 512 + wid * 128 + c);
                acc[tk] += sv.x * cg[0] + sv.y * cg[1] + sv.z * cg[2] + sv.w * cg[3];
            }
        }
    }

    // ssq reduce within each 16-thread group (one token per group)
    #pragma unroll
    for (int m = 1; m < 16; m <<= 1) ssq += __shfl_xor(ssq, m);
    if ((tid & 15) == 0)
        scale_sh[my_tk] = 64.0f / fmaxf(sqrtf(ssq), 1e-12f);

    #pragma unroll
    for (int tk = 0; tk < 16; ++tk) part[wid * 1024 + tk * 64 + d] = acc[tk];
    __syncthreads();

    const int d2 = tid & 63, grp = tid >> 6;
    #pragma unroll
    for (int tt = 0; tt < 4; ++tt) {
        const int tk = grp * 4 + tt;
        float v = part[0 * 1024 + tk * 64 + d2] + part[1 * 1024 + tk * 64 + d2] +
                  part[2 * 1024 + tk * 64 + d2] + part[3 * 1024 + tk * 64 + d2];
        code[(size_t)(tok0 + tk) * 64 + d2] = v * scale_sh[tk];
    }
}

// ---------------- wave-parallel log-domain Sinkhorn ----------------
template <int ROWS, int COLS, int J>
__device__ inline void wave_sinkhorn(const float* Z, float* P)
{
    const float lr = -logf((float)ROWS);
    const float lc = -logf((float)COLS);
    float u[J], v[J];
    #pragma unroll
    for (int j = 0; j < J; ++j) { u[j] = 0.f; v[j] = 0.f; }

    for (int it = 0; it < ITERS; ++it) {
        float t[J], m[J], sm[J];
        #pragma unroll
        for (int j = 0; j < J; ++j) { t[j] = Z[j] + v[j]; m[j] = t[j]; }
        #pragma unroll
        for (int mask = 1; mask < COLS; mask <<= 1)
            #pragma unroll
            for (int j = 0; j < J; ++j) m[j] = fmaxf(m[j], __shfl_xor(m[j], mask));
        #pragma unroll
        for (int j = 0; j < J; ++j) sm[j] = expf(t[j] - m[j]);
        #pragma unroll
        for (int mask = 1; mask < COLS; mask <<= 1)
            #pragma unroll
            for (int j = 0; j < J; ++j) sm[j] += __shfl_xor(sm[j], mask);
        #pragma unroll
        for (int j = 0; j < J; ++j) u[j] = lr - (m[j] + logf(sm[j]));

        #pragma unroll
        for (int j = 0; j < J; ++j) t[j] = Z[j] + u[j];
        float mm = t[0];
        #pragma unroll
        for (int j = 1; j < J; ++j) mm = fmaxf(mm, t[j]);
        #pragma unroll
        for (int mask = COLS; mask < 64; mask <<= 1) mm = fmaxf(mm, __shfl_xor(mm, mask));
        float ss = 0.f;
        #pragma unroll
        for (int j = 0; j < J; ++j) ss += expf(t[j] - mm);
        #pragma unroll
        for (int mask = COLS; mask < 64; mask <<= 1) ss += __shfl_xor(ss, mask);
        const float vv = lc - (mm + logf(ss));
        #pragma unroll
        for (int j = 0; j < J; ++j) v[j] = vv;
    }
    #pragma unroll
    for (int j = 0; j < J; ++j) P[j] = expf(Z[j] + u[j] + v[j]) * (float)ROWS;
}

// ---------------- Kernel B: logits -> 4 sinkhorns -> P_na/P_np + layer_in(bf16) ----------------
__global__ __launch_bounds__(256) void k_route(const float* __restrict__ s,
                                               const float* __restrict__ code,
                                               const float* __restrict__ a_pre_p, const float* __restrict__ tl_pre, const float* __restrict__ H_pre,
                                               const float* __restrict__ a_al_p,  const float* __restrict__ tl_al,  const float* __restrict__ H_al,
                                               const float* __restrict__ a_nx_p,  const float* __restrict__ tl_nx,  const float* __restrict__ H_nx,
                                               const float* __restrict__ a_po_p,  const float* __restrict__ tl_po,  const float* __restrict__ H_po,
                                               unsigned short* __restrict__ layer_in,
                                               float* __restrict__ Pna, float* __restrict__ Pnp)
{
    __shared__ float code_sh[64];
    __shared__ float s_sh[SD];
    __shared__ float Ppre_sh[64], Pal_sh[256], Pnx_sh[256], Ppo_sh[64];
    const int tid  = threadIdx.x;
    const int lane = tid & 63;
    const int wid  = tid >> 6;
    const int tok  = blockIdx.x;

    if (tid < 64) code_sh[tid] = code[(size_t)tok * 64 + tid];
    {
        const float4* sp4 = (const float4*)(s + (size_t)tok * SD);
        float4* d4 = (float4*)s_sh;
        #pragma unroll
        for (int j = 0; j < 4; ++j) d4[j * 256 + tid] = sp4[j * 256 + tid];
    }
    __syncthreads();

    if (wid == 0) {            // pre: 4 x 16
        float raw = 0.f;
        for (int dd = 0; dd < 64; ++dd) raw += code_sh[dd] * tl_pre[dd * 64 + lane];
        float Z[1], P[1];
        Z[0] = (*a_pre_p) * raw + H_pre[lane];
        wave_sinkhorn<4, 16, 1>(Z, P);
        Ppre_sh[lane] = P[0];
    } else if (wid == 1) {     // align: 16 x 16
        float raw[4] = {0.f, 0.f, 0.f, 0.f};
        for (int dd = 0; dd < 64; ++dd) {
            const float cdv = code_sh[dd];
            #pragma unroll
            for (int j = 0; j < 4; ++j) raw[j] += cdv * tl_al[dd * 256 + j * 64 + lane];
        }
        const float aa = *a_al_p;
        float Z[4], P[4];
        #pragma unroll
        for (int j = 0; j < 4; ++j) Z[j] = aa * raw[j] + H_al[j * 64 + lane];
        wave_sinkhorn<16, 16, 4>(Z, P);
        #pragma unroll
        for (int j = 0; j < 4; ++j) Pal_sh[j * 64 + lane] = P[j];
    } else if (wid == 2) {     // next: 16 x 16
        float raw[4] = {0.f, 0.f, 0.f, 0.f};
        for (int dd = 0; dd < 64; ++dd) {
            const float cdv = code_sh[dd];
            #pragma unroll
            for (int j = 0; j < 4; ++j) raw[j] += cdv * tl_nx[dd * 256 + j * 64 + lane];
        }
        const float aa = *a_nx_p;
        float Z[4], P[4];
        #pragma unroll
        for (int j = 0; j < 4; ++j) Z[j] = aa * raw[j] + H_nx[j * 64 + lane];
        wave_sinkhorn<16, 16, 4>(Z, P);
        #pragma unroll
        for (int j = 0; j < 4; ++j) Pnx_sh[j * 64 + lane] = P[j];
    } else {                   // post: 16 x 4
        float raw = 0.f;
        for (int dd = 0; dd < 64; ++dd) raw += code_sh[dd] * tl_po[dd * 64 + lane];
        float Z[1], P[1];
        Z[0] = (*a_po_p) * raw + H_po[lane];
        wave_sinkhorn<16, 4, 1>(Z, P);
        Ppo_sh[lane] = P[0];
    }
    __syncthreads();

    {   // P_na = P_next @ P_align
        const int m = tid >> 4, jj = tid & 15;
        float acc = 0.f;
        #pragma unroll
        for (int t2 = 0; t2 < 16; ++t2) acc += Pnx_sh[m * 16 + t2] * Pal_sh[t2 * 16 + jj];
        Pna[(size_t)tok * 256 + tid] = acc;
    }
    if (tid < 64) {  // P_np = P_next @ P_post
        const int m = tid >> 2, q = tid & 3;
        float acc = 0.f;
        #pragma unroll
        for (int t2 = 0; t2 < 16; ++t2) acc += Pnx_sh[m * 16 + t2] * Ppo_sh[t2 * 4 + q];
        Pnp[(size_t)tok * 64 + tid] = acc;
    }
    {   // layer_in (bf16): [i*256+c] = sum_j Ppre[i][j] * s[j*256+c]
        const int c = tid;
        #pragma unroll
        for (int i = 0; i < 4; ++i) {
            float acc = 0.f;
            #pragma unroll
            for (int j = 0; j < 16; ++j) acc += Ppre_sh[i * 16 + j] * s_sh[j * 256 + c];
            layer_in[(size_t)tok * 1024 + i * 256 + c] = f2bf(acc);
        }
    }
}

// ---------------- Kernel W: transpose + convert W -> WT bf16 [n][k] ----------------
__global__ __launch_bounds__(256) void k_wt(const float* __restrict__ W,
                                            unsigned short* __restrict__ WT)
{
    __shared__ float tb[64][65];
    const int k0 = blockIdx.y * 64, n0 = blockIdx.x * 64;
    #pragma unroll 4
    for (int q = 0; q < 16; ++q) {
        const int idx = q * 256 + threadIdx.x;
        const int r = idx >> 6, c = idx & 63;
        tb[r][c] = W[(size_t)(k0 + r) * 1024 + n0 + c];
    }
    __syncthreads();
    #pragma unroll 4
    for (int q = 0; q < 16; ++q) {
        const int idx = q * 256 + threadIdx.x;
        const int n = idx >> 6, k = idx & 63;
        WT[(size_t)(n0 + n) * 1024 + k0 + k] = f2bf(tb[k][n]);
    }
}

// ---------------- Kernel C: layer_out = layer_in @ WT^T via bf16 MFMA ----------------
// C[8192][1024] f32 = A[8192][1024]bf16 @ B; B[k][n] = WT[n][k].
__global__ __launch_bounds__(256) void k_gemm_bf16(const unsigned short* __restrict__ A,
                                                   const unsigned short* __restrict__ BT,
                                                   float* __restrict__ C)
{
    __shared__ unsigned short Abuf[128 * 48];  // [row][48], 32 used + 16 pad
    __shared__ unsigned short Bbuf[128 * 48];
    const int tid  = threadIdx.x;
    const int lane = tid & 63;
    const int wid  = tid >> 6;
    const int wr   = wid >> 1, wc = wid & 1;
    const int m0 = blockIdx.y * 128, n0 = blockIdx.x * 128;

    f32x4 acc[4][4];
    #pragma unroll
    for (int mi = 0; mi < 4; ++mi)
        #pragma unroll
        for (int ni = 0; ni < 4; ++ni) acc[mi][ni] = (f32x4){0.f, 0.f, 0.f, 0.f};

    for (int k0 = 0; k0 < 1024; k0 += 32) {
        __syncthreads();  // WAR guard
        #pragma unroll
        for (int h = 0; h < 2; ++h) {
            const int idx = h * 256 + tid;
            const int row = idx >> 2, kq = idx & 3;  // 4x8-half chunks per row
            float4 av = *(const float4*)(A + (size_t)(m0 + row) * 1024 + k0 + kq * 8);
            *(float4*)(Abuf + row * 48 + kq * 8) = av;
            float4 bv = *(const float4*)(BT + (size_t)(n0 + row) * 1024 + k0 + kq * 8);
            *(float4*)(Bbuf + row * 48 + kq * 8) = bv;
        }
        __syncthreads();

        short8 a[4], b[4];
        #pragma unroll
        for (int mi = 0; mi < 4; ++mi)
            a[mi] = *(const short8*)(Abuf + (wr * 64 + mi * 16 + (lane & 15)) * 48 + (lane >> 4) * 8);
        #pragma unroll
        for (int ni = 0; ni < 4; ++ni)
            b[ni] = *(const short8*)(Bbuf + (wc * 64 + ni * 16 + (lane & 15)) * 48 + (lane >> 4) * 8);
        #pragma unroll
        for (int mi = 0; mi < 4; ++mi)
            #pragma unroll
            for (int ni = 0; ni < 4; ++ni)
                acc[mi][ni] = __builtin_amdgcn_mfma_f32_16x16x32_bf16(a[mi], b[ni], acc[mi][ni], 0, 0, 0);
    }

    // C/D layout: col = lane&15, row = (lane>>4)*4 + r
    #pragma unroll
    for (int mi = 0; mi < 4; ++mi)
        #pragma unroll
        for (int ni = 0; ni < 4; ++ni)
            #pragma unroll
            for (int r = 0; r < 4; ++r)
                C[(size_t)(m0 + wr * 64 + mi * 16 + (lane >> 4) * 4 + r) * 1024 +
                  n0 + wc * 64 + ni * 16 + (lane & 15)] = acc[mi][ni][r];
}

// ---------------- Kernel D: s_next = P_na @ s + P_np @ layer_out ----------------
__global__ __launch_bounds__(256) void k_final(const float* __restrict__ s,
                                               const float* __restrict__ lo,
                                               const float* __restrict__ Pna,
                                               const float* __restrict__ Pnp,
                                               float* __restrict__ out)
{
    __shared__ float s_sh[SD];
    __shared__ float lo_sh[1024];
    __shared__ float Pna_sh[256];
    __shared__ float Pnp_sh[64];
    const int tid = threadIdx.x;
    const int tok = blockIdx.x;

    {
        const float4* sp4 = (const float4*)(s + (size_t)tok * SD);
        float4* d4 = (float4*)s_sh;
        #pragma unroll
        for (int j = 0; j < 4; ++j) d4[j * 256 + tid] = sp4[j * 256 + tid];
        ((float4*)lo_sh)[tid] = ((const float4*)(lo + (size_t)tok * 1024))[tid];
        Pna_sh[tid] = Pna[(size_t)tok * 256 + tid];
        if (tid < 64) Pnp_sh[tid] = Pnp[(size_t)tok * 64 + tid];
    }
    __syncthreads();

    const int c = tid;
    #pragma unroll
    for (int m = 0; m < 16; ++m) {
        float acc = 0.f;
        #pragma unroll
        for (int j = 0; j < 16; ++j) acc += Pna_sh[m * 16 + j] * s_sh[j * 256 + c];
        #pragma unroll
        for (int q = 0; q < 4; ++q) acc += Pnp_sh[m * 4 + q] * lo_sh[q * 256 + c];
        out[(size_t)tok * SD + m * 256 + c] = acc;
    }
}

extern "C" void kernel_launch(void* const* d_in, const int* in_sizes, int n_in,
                              void* d_out, int out_size, void* d_ws, size_t ws_size,
                              hipStream_t stream)
{
    const float* s        = (const float*)d_in[0];
    const float* gamma    = (const float*)d_in[1];
    const float* compress = (const float*)d_in[2];
    const float* a_pre    = (const float*)d_in[3];
    const float* tl_pre   = (const float*)d_in[4];
    const float* H_pre    = (const float*)d_in[5];
    const float* a_al     = (const float*)d_in[6];
    const float* tl_al    = (const float*)d_in[7];
    const float* H_al     = (const float*)d_in[8];
    const float* a_nx     = (const float*)d_in[9];
    const float* tl_nx    = (const float*)d_in[10];
    const float* H_nx     = (const float*)d_in[11];
    const float* a_po     = (const float*)d_in[12];
    const float* tl_po    = (const float*)d_in[13];
    const float* H_po     = (const float*)d_in[14];
    const float* W        = (const float*)d_in[15];
    float* out = (float*)d_out;

    float* code              = (float*)d_ws;                         // 8192*64 f32
    float* layer_out         = code + (size_t)8192 * 64;             // 8192*1024 f32
    float* Pna               = layer_out + (size_t)8192 * 1024;      // 8192*256 f32
    float* Pnp               = Pna + (size_t)8192 * 256;             // 8192*64 f32
    unsigned short* layer_in = (unsigned short*)(Pnp + (size_t)8192 * 64);  // 8192*1024 bf16
    unsigned short* WT       = layer_in + (size_t)8192 * 1024;       // 1024*1024 bf16

    k_wt<<<dim3(16, 16), 256, 0, stream>>>(W, WT);
    k_code2<<<512, 256, 0, stream>>>(s, gamma, compress, code);
    k_route<<<NTOK, 256, 0, stream>>>(s, code,
                                      a_pre, tl_pre, H_pre,
                                      a_al,  tl_al,  H_al,
                                      a_nx,  tl_nx,  H_nx,
                                      a_po,  tl_po,  H_po,
                                      layer_in, Pna, Pnp);
    k_gemm_bf16<<<dim3(8, 64), 256, 0, stream>>>(layer_in, WT, layer_out);
    k_final<<<NTOK, 256, 0, stream>>>(s, layer_out, Pna, Pnp, out);
}

// Round 3
// 352.776 us; speedup vs baseline: 2.3287x; 1.4619x over previous
//
#include <hip/hip_runtime.h>
#include <math.h>

#define NTOK 8192
#define SD   4096
#define ITERS 20

typedef __attribute__((ext_vector_type(8))) short short8;
typedef __attribute__((ext_vector_type(8))) unsigned short ushort8;
typedef __attribute__((ext_vector_type(4))) float f32x4;

__device__ inline unsigned short f2bf(float x) {
    unsigned int u = __float_as_uint(x);
    unsigned int r = (u + 0x7FFFu + ((u >> 16) & 1u)) >> 16;
    return (unsigned short)r;
}

// ---------------- Kernel P: cgT[d][k] = bf16(compress[k][d] * (gamma[k]+1)) ----------------
__global__ __launch_bounds__(256) void k_prep(const float* __restrict__ compress,
                                              const float* __restrict__ gamma,
                                              unsigned short* __restrict__ cgT)
{
    __shared__ float tb[64][65];
    __shared__ float gsh[64];
    const int tid = threadIdx.x;
    const int k0 = blockIdx.x * 64;
    #pragma unroll 4
    for (int q = 0; q < 16; ++q) {
        const int idx = q * 256 + tid;
        const int r = idx >> 6, dd = idx & 63;
        tb[r][dd] = compress[(size_t)(k0 + r) * 64 + dd];
    }
    if (tid < 64) gsh[tid] = gamma[k0 + tid] + 1.0f;
    __syncthreads();
    #pragma unroll 4
    for (int q = 0; q < 16; ++q) {
        const int idx = q * 256 + tid;
        const int d = idx >> 6, r = idx & 63;
        cgT[(size_t)d * SD + k0 + r] = f2bf(tb[r][d] * gsh[r]);
    }
}

// ---------------- Kernel A: code = rmsnorm-scale * (s @ cg) via bf16 MFMA ----------------
// 256 blocks x 32 tokens. Wave w covers interleaved K-slices [ks*128 + w*32, +32).
// ssq accumulated from f32 during staging; scale applied at the end.
__global__ __launch_bounds__(256) void k_code3(const float* __restrict__ s,
                                               const unsigned short* __restrict__ cgT,
                                               float* __restrict__ code)
{
    __shared__ __align__(16) unsigned short s_sh[32 * 152];
    __shared__ __align__(16) unsigned short cg_sh[64 * 152];
    __shared__ float red[4 * 32 * 68];
    __shared__ float ssq_sh[32];
    const int tid  = threadIdx.x;
    const int lane = tid & 63;
    const int wid  = tid >> 6;
    const int tok0 = blockIdx.x * 32;
    const int st_tok = tid >> 3, st_k = (tid & 7) * 16;   // s staging: 16 bf16/thread
    const int sg_d   = tid >> 2, sg_k = (tid & 3) * 32;   // cg staging: 32 bf16/thread
    const int wk = wid * 32;

    float ssq = 0.f;
    f32x4 acc[2][4];
    #pragma unroll
    for (int mi = 0; mi < 2; ++mi)
        #pragma unroll
        for (int ni = 0; ni < 4; ++ni) acc[mi][ni] = (f32x4){0.f, 0.f, 0.f, 0.f};

    for (int ks = 0; ks < 32; ++ks) {
        const int kg = ks * 128;
        __syncthreads();  // WAR guard on s_sh/cg_sh
        // stage s (f32 -> bf16), fuse ssq
        {
            const float4* sp = (const float4*)(s + (size_t)(tok0 + st_tok) * SD + kg + st_k);
            float4 v0 = sp[0], v1 = sp[1], v2 = sp[2], v3 = sp[3];
            ssq += v0.x*v0.x + v0.y*v0.y + v0.z*v0.z + v0.w*v0.w
                 + v1.x*v1.x + v1.y*v1.y + v1.z*v1.z + v1.w*v1.w
                 + v2.x*v2.x + v2.y*v2.y + v2.z*v2.z + v2.w*v2.w
                 + v3.x*v3.x + v3.y*v3.y + v3.z*v3.z + v3.w*v3.w;
            ushort8 lo, hi;
            lo[0]=f2bf(v0.x); lo[1]=f2bf(v0.y); lo[2]=f2bf(v0.z); lo[3]=f2bf(v0.w);
            lo[4]=f2bf(v1.x); lo[5]=f2bf(v1.y); lo[6]=f2bf(v1.z); lo[7]=f2bf(v1.w);
            hi[0]=f2bf(v2.x); hi[1]=f2bf(v2.y); hi[2]=f2bf(v2.z); hi[3]=f2bf(v2.w);
            hi[4]=f2bf(v3.x); hi[5]=f2bf(v3.y); hi[6]=f2bf(v3.z); hi[7]=f2bf(v3.w);
            ushort8* sw = (ushort8*)(s_sh + st_tok * 152 + st_k);
            sw[0] = lo; sw[1] = hi;
        }
        // stage cgT (already bf16, from L2)
        {
            const ushort8* gp = (const ushort8*)(cgT + (size_t)sg_d * SD + kg + sg_k);
            ushort8 c0 = gp[0], c1 = gp[1], c2 = gp[2], c3 = gp[3];
            ushort8* cw = (ushort8*)(cg_sh + sg_d * 152 + sg_k);
            cw[0] = c0; cw[1] = c1; cw[2] = c2; cw[3] = c3;
        }
        __syncthreads();

        short8 a[2], b[4];
        #pragma unroll
        for (int mi = 0; mi < 2; ++mi)
            a[mi] = *(const short8*)(s_sh + (mi * 16 + (lane & 15)) * 152 + wk + (lane >> 4) * 8);
        #pragma unroll
        for (int ni = 0; ni < 4; ++ni)
            b[ni] = *(const short8*)(cg_sh + (ni * 16 + (lane & 15)) * 152 + wk + (lane >> 4) * 8);
        #pragma unroll
        for (int mi = 0; mi < 2; ++mi)
            #pragma unroll
            for (int ni = 0; ni < 4; ++ni)
                acc[mi][ni] = __builtin_amdgcn_mfma_f32_16x16x32_bf16(a[mi], b[ni], acc[mi][ni], 0, 0, 0);
    }

    // ssq: reduce across the 8 threads sharing a token (consecutive lanes)
    ssq += __shfl_xor(ssq, 1);
    ssq += __shfl_xor(ssq, 2);
    ssq += __shfl_xor(ssq, 4);
    if ((tid & 7) == 0) ssq_sh[st_tok] = ssq;

    // write per-wave partials: C/D layout col=lane&15, row=(lane>>4)*4+r
    #pragma unroll
    for (int mi = 0; mi < 2; ++mi)
        #pragma unroll
        for (int ni = 0; ni < 4; ++ni)
            #pragma unroll
            for (int r = 0; r < 4; ++r)
                red[wid * 2176 + (mi * 16 + (lane >> 4) * 4 + r) * 68 + ni * 16 + (lane & 15)] = acc[mi][ni][r];
    __syncthreads();
    if (tid < 32) ssq_sh[tid] = 64.0f / fmaxf(sqrtf(ssq_sh[tid]), 1e-12f);
    __syncthreads();

    #pragma unroll
    for (int q = 0; q < 8; ++q) {
        const int idx = q * 256 + tid;
        const int tok = idx >> 6, d = idx & 63;
        float v = red[0 * 2176 + tok * 68 + d] + red[1 * 2176 + tok * 68 + d]
                + red[2 * 2176 + tok * 68 + d] + red[3 * 2176 + tok * 68 + d];
        code[(size_t)(tok0 + tok) * 64 + d] = v * ssq_sh[tok];
    }
}

// ---------------- wave-parallel log-domain Sinkhorn ----------------
template <int ROWS, int COLS, int J>
__device__ inline void wave_sinkhorn(const float* Z, float* P)
{
    const float lr = -logf((float)ROWS);
    const float lc = -logf((float)COLS);
    float u[J], v[J];
    #pragma unroll
    for (int j = 0; j < J; ++j) { u[j] = 0.f; v[j] = 0.f; }

    for (int it = 0; it < ITERS; ++it) {
        float t[J], m[J], sm[J];
        #pragma unroll
        for (int j = 0; j < J; ++j) { t[j] = Z[j] + v[j]; m[j] = t[j]; }
        #pragma unroll
        for (int mask = 1; mask < COLS; mask <<= 1)
            #pragma unroll
            for (int j = 0; j < J; ++j) m[j] = fmaxf(m[j], __shfl_xor(m[j], mask));
        #pragma unroll
        for (int j = 0; j < J; ++j) sm[j] = expf(t[j] - m[j]);
        #pragma unroll
        for (int mask = 1; mask < COLS; mask <<= 1)
            #pragma unroll
            for (int j = 0; j < J; ++j) sm[j] += __shfl_xor(sm[j], mask);
        #pragma unroll
        for (int j = 0; j < J; ++j) u[j] = lr - (m[j] + logf(sm[j]));

        #pragma unroll
        for (int j = 0; j < J; ++j) t[j] = Z[j] + u[j];
        float mm = t[0];
        #pragma unroll
        for (int j = 1; j < J; ++j) mm = fmaxf(mm, t[j]);
        #pragma unroll
        for (int mask = COLS; mask < 64; mask <<= 1) mm = fmaxf(mm, __shfl_xor(mm, mask));
        float ss = 0.f;
        #pragma unroll
        for (int j = 0; j < J; ++j) ss += expf(t[j] - mm);
        #pragma unroll
        for (int mask = COLS; mask < 64; mask <<= 1) ss += __shfl_xor(ss, mask);
        const float vv = lc - (mm + logf(ss));
        #pragma unroll
        for (int j = 0; j < J; ++j) v[j] = vv;
    }
    #pragma unroll
    for (int j = 0; j < J; ++j) P[j] = expf(Z[j] + u[j] + v[j]) * (float)ROWS;
}

// ---------------- Kernel B: logits -> 4 sinkhorns -> P_na/P_np + layer_in(bf16) ----------------
__global__ __launch_bounds__(256) void k_route(const float* __restrict__ s,
                                               const float* __restrict__ code,
                                               const float* __restrict__ a_pre_p, const float* __restrict__ tl_pre, const float* __restrict__ H_pre,
                                               const float* __restrict__ a_al_p,  const float* __restrict__ tl_al,  const float* __restrict__ H_al,
                                               const float* __restrict__ a_nx_p,  const float* __restrict__ tl_nx,  const float* __restrict__ H_nx,
                                               const float* __restrict__ a_po_p,  const float* __restrict__ tl_po,  const float* __restrict__ H_po,
                                               unsigned short* __restrict__ layer_in,
                                               float* __restrict__ Pna, float* __restrict__ Pnp)
{
    __shared__ float code_sh[64];
    __shared__ float s_sh[SD];
    __shared__ float Ppre_sh[64], Pal_sh[256], Pnx_sh[256], Ppo_sh[64];
    const int tid  = threadIdx.x;
    const int lane = tid & 63;
    const int wid  = tid >> 6;
    const int tok  = blockIdx.x;

    if (tid < 64) code_sh[tid] = code[(size_t)tok * 64 + tid];
    {
        const float4* sp4 = (const float4*)(s + (size_t)tok * SD);
        float4* d4 = (float4*)s_sh;
        #pragma unroll
        for (int j = 0; j < 4; ++j) d4[j * 256 + tid] = sp4[j * 256 + tid];
    }
    __syncthreads();

    if (wid == 0) {            // pre: 4 x 16
        float raw = 0.f;
        for (int dd = 0; dd < 64; ++dd) raw += code_sh[dd] * tl_pre[dd * 64 + lane];
        float Z[1], P[1];
        Z[0] = (*a_pre_p) * raw + H_pre[lane];
        wave_sinkhorn<4, 16, 1>(Z, P);
        Ppre_sh[lane] = P[0];
    } else if (wid == 1) {     // align: 16 x 16
        float raw[4] = {0.f, 0.f, 0.f, 0.f};
        for (int dd = 0; dd < 64; ++dd) {
            const float cdv = code_sh[dd];
            #pragma unroll
            for (int j = 0; j < 4; ++j) raw[j] += cdv * tl_al[dd * 256 + j * 64 + lane];
        }
        const float aa = *a_al_p;
        float Z[4], P[4];
        #pragma unroll
        for (int j = 0; j < 4; ++j) Z[j] = aa * raw[j] + H_al[j * 64 + lane];
        wave_sinkhorn<16, 16, 4>(Z, P);
        #pragma unroll
        for (int j = 0; j < 4; ++j) Pal_sh[j * 64 + lane] = P[j];
    } else if (wid == 2) {     // next: 16 x 16
        float raw[4] = {0.f, 0.f, 0.f, 0.f};
        for (int dd = 0; dd < 64; ++dd) {
            const float cdv = code_sh[dd];
            #pragma unroll
            for (int j = 0; j < 4; ++j) raw[j] += cdv * tl_nx[dd * 256 + j * 64 + lane];
        }
        const float aa = *a_nx_p;
        float Z[4], P[4];
        #pragma unroll
        for (int j = 0; j < 4; ++j) Z[j] = aa * raw[j] + H_nx[j * 64 + lane];
        wave_sinkhorn<16, 16, 4>(Z, P);
        #pragma unroll
        for (int j = 0; j < 4; ++j) Pnx_sh[j * 64 + lane] = P[j];
    } else {                   // post: 16 x 4
        float raw = 0.f;
        for (int dd = 0; dd < 64; ++dd) raw += code_sh[dd] * tl_po[dd * 64 + lane];
        float Z[1], P[1];
        Z[0] = (*a_po_p) * raw + H_po[lane];
        wave_sinkhorn<16, 4, 1>(Z, P);
        Ppo_sh[lane] = P[0];
    }
    __syncthreads();

    {   // P_na = P_next @ P_align
        const int m = tid >> 4, jj = tid & 15;
        float acc = 0.f;
        #pragma unroll
        for (int t2 = 0; t2 < 16; ++t2) acc += Pnx_sh[m * 16 + t2] * Pal_sh[t2 * 16 + jj];
        Pna[(size_t)tok * 256 + tid] = acc;
    }
    if (tid < 64) {  // P_np = P_next @ P_post
        const int m = tid >> 2, q = tid & 3;
        float acc = 0.f;
        #pragma unroll
        for (int t2 = 0; t2 < 16; ++t2) acc += Pnx_sh[m * 16 + t2] * Ppo_sh[t2 * 4 + q];
        Pnp[(size_t)tok * 64 + tid] = acc;
    }
    {   // layer_in (bf16): [i*256+c] = sum_j Ppre[i][j] * s[j*256+c]
        const int c = tid;
        #pragma unroll
        for (int i = 0; i < 4; ++i) {
            float acc = 0.f;
            #pragma unroll
            for (int j = 0; j < 16; ++j) acc += Ppre_sh[i * 16 + j] * s_sh[j * 256 + c];
            layer_in[(size_t)tok * 1024 + i * 256 + c] = f2bf(acc);
        }
    }
}

// ---------------- Kernel W: transpose + convert W -> WT bf16 [n][k] ----------------
__global__ __launch_bounds__(256) void k_wt(const float* __restrict__ W,
                                            unsigned short* __restrict__ WT)
{
    __shared__ float tb[64][65];
    const int k0 = blockIdx.y * 64, n0 = blockIdx.x * 64;
    #pragma unroll 4
    for (int q = 0; q < 16; ++q) {
        const int idx = q * 256 + threadIdx.x;
        const int r = idx >> 6, c = idx & 63;
        tb[r][c] = W[(size_t)(k0 + r) * 1024 + n0 + c];
    }
    __syncthreads();
    #pragma unroll 4
    for (int q = 0; q < 16; ++q) {
        const int idx = q * 256 + threadIdx.x;
        const int n = idx >> 6, k = idx & 63;
        WT[(size_t)(n0 + n) * 1024 + k0 + k] = f2bf(tb[k][n]);
    }
}

// ---------------- Kernel C: layer_out = layer_in @ WT^T via bf16 MFMA ----------------
__global__ __launch_bounds__(256) void k_gemm_bf16(const unsigned short* __restrict__ A,
                                                   const unsigned short* __restrict__ BT,
                                                   float* __restrict__ C)
{
    __shared__ unsigned short Abuf[128 * 48];
    __shared__ unsigned short Bbuf[128 * 48];
    const int tid  = threadIdx.x;
    const int lane = tid & 63;
    const int wid  = tid >> 6;
    const int wr   = wid >> 1, wc = wid & 1;
    const int m0 = blockIdx.y * 128, n0 = blockIdx.x * 128;

    f32x4 acc[4][4];
    #pragma unroll
    for (int mi = 0; mi < 4; ++mi)
        #pragma unroll
        for (int ni = 0; ni < 4; ++ni) acc[mi][ni] = (f32x4){0.f, 0.f, 0.f, 0.f};

    for (int k0 = 0; k0 < 1024; k0 += 32) {
        __syncthreads();
        #pragma unroll
        for (int h = 0; h < 2; ++h) {
            const int idx = h * 256 + tid;
            const int row = idx >> 2, kq = idx & 3;
            float4 av = *(const float4*)(A + (size_t)(m0 + row) * 1024 + k0 + kq * 8);
            *(float4*)(Abuf + row * 48 + kq * 8) = av;
            float4 bv = *(const float4*)(BT + (size_t)(n0 + row) * 1024 + k0 + kq * 8);
            *(float4*)(Bbuf + row * 48 + kq * 8) = bv;
        }
        __syncthreads();

        short8 a[4], b[4];
        #pragma unroll
        for (int mi = 0; mi < 4; ++mi)
            a[mi] = *(const short8*)(Abuf + (wr * 64 + mi * 16 + (lane & 15)) * 48 + (lane >> 4) * 8);
        #pragma unroll
        for (int ni = 0; ni < 4; ++ni)
            b[ni] = *(const short8*)(Bbuf + (wc * 64 + ni * 16 + (lane & 15)) * 48 + (lane >> 4) * 8);
        #pragma unroll
        for (int mi = 0; mi < 4; ++mi)
            #pragma unroll
            for (int ni = 0; ni < 4; ++ni)
                acc[mi][ni] = __builtin_amdgcn_mfma_f32_16x16x32_bf16(a[mi], b[ni], acc[mi][ni], 0, 0, 0);
    }

    #pragma unroll
    for (int mi = 0; mi < 4; ++mi)
        #pragma unroll
        for (int ni = 0; ni < 4; ++ni)
            #pragma unroll
            for (int r = 0; r < 4; ++r)
                C[(size_t)(m0 + wr * 64 + mi * 16 + (lane >> 4) * 4 + r) * 1024 +
                  n0 + wc * 64 + ni * 16 + (lane & 15)] = acc[mi][ni][r];
}

// ---------------- Kernel D: s_next = P_na @ s + P_np @ layer_out ----------------
__global__ __launch_bounds__(256) void k_final(const float* __restrict__ s,
                                               const float* __restrict__ lo,
                                               const float* __restrict__ Pna,
                                               const float* __restrict__ Pnp,
                                               float* __restrict__ out)
{
    __shared__ float s_sh[SD];
    __shared__ float lo_sh[1024];
    __shared__ float Pna_sh[256];
    __shared__ float Pnp_sh[64];
    const int tid = threadIdx.x;
    const int tok = blockIdx.x;

    {
        const float4* sp4 = (const float4*)(s + (size_t)tok * SD);
        float4* d4 = (float4*)s_sh;
        #pragma unroll
        for (int j = 0; j < 4; ++j) d4[j * 256 + tid] = sp4[j * 256 + tid];
        ((float4*)lo_sh)[tid] = ((const float4*)(lo + (size_t)tok * 1024))[tid];
        Pna_sh[tid] = Pna[(size_t)tok * 256 + tid];
        if (tid < 64) Pnp_sh[tid] = Pnp[(size_t)tok * 64 + tid];
    }
    __syncthreads();

    const int c = tid;
    #pragma unroll
    for (int m = 0; m < 16; ++m) {
        float acc = 0.f;
        #pragma unroll
        for (int j = 0; j < 16; ++j) acc += Pna_sh[m * 16 + j] * s_sh[j * 256 + c];
        #pragma unroll
        for (int q = 0; q < 4; ++q) acc += Pnp_sh[m * 4 + q] * lo_sh[q * 256 + c];
        out[(size_t)tok * SD + m * 256 + c] = acc;
    }
}

extern "C" void kernel_launch(void* const* d_in, const int* in_sizes, int n_in,
                              void* d_out, int out_size, void* d_ws, size_t ws_size,
                              hipStream_t stream)
{
    const float* s        = (const float*)d_in[0];
    const float* gamma    = (const float*)d_in[1];
    const float* compress = (const float*)d_in[2];
    const float* a_pre    = (const float*)d_in[3];
    const float* tl_pre   = (const float*)d_in[4];
    const float* H_pre    = (const float*)d_in[5];
    const float* a_al     = (const float*)d_in[6];
    const float* tl_al    = (const float*)d_in[7];
    const float* H_al     = (const float*)d_in[8];
    const float* a_nx     = (const float*)d_in[9];
    const float* tl_nx    = (const float*)d_in[10];
    const float* H_nx     = (const float*)d_in[11];
    const float* a_po     = (const float*)d_in[12];
    const float* tl_po    = (const float*)d_in[13];
    const float* H_po     = (const float*)d_in[14];
    const float* W        = (const float*)d_in[15];
    float* out = (float*)d_out;

    float* code              = (float*)d_ws;                         // 8192*64 f32
    float* layer_out         = code + (size_t)8192 * 64;             // 8192*1024 f32
    float* Pna               = layer_out + (size_t)8192 * 1024;      // 8192*256 f32
    float* Pnp               = Pna + (size_t)8192 * 256;             // 8192*64 f32
    unsigned short* layer_in = (unsigned short*)(Pnp + (size_t)8192 * 64);  // 8192*1024 bf16
    unsigned short* WT       = layer_in + (size_t)8192 * 1024;       // 1024*1024 bf16
    unsigned short* cgT      = WT + (size_t)1024 * 1024;             // 64*4096 bf16

    k_wt<<<dim3(16, 16), 256, 0, stream>>>(W, WT);
    k_prep<<<64, 256, 0, stream>>>(compress, gamma, cgT);
    k_code3<<<256, 256, 0, stream>>>(s, cgT, code);
    k_route<<<NTOK, 256, 0, stream>>>(s, code,
                                      a_pre, tl_pre, H_pre,
                                      a_al,  tl_al,  H_al,
                                      a_nx,  tl_nx,  H_nx,
                                      a_po,  tl_po,  H_po,
                                      layer_in, Pna, Pnp);
    k_gemm_bf16<<<dim3(8, 64), 256, 0, stream>>>(layer_in, WT, layer_out);
    k_final<<<NTOK, 256, 0, stream>>>(s, layer_out, Pna, Pnp, out);
}

// Round 4
// 249.313 us; speedup vs baseline: 3.2951x; 1.4150x over previous
//
#include <hip/hip_runtime.h>
#include <math.h>

#define NTOK 8192
#define SD   4096
#define ITERS 20

typedef __attribute__((ext_vector_type(8))) short short8;
typedef __attribute__((ext_vector_type(8))) unsigned short ushort8;
typedef __attribute__((ext_vector_type(4))) float f32x4;

__device__ inline unsigned short f2bf(float x) {
    unsigned int u = __float_as_uint(x);
    unsigned int r = (u + 0x7FFFu + ((u >> 16) & 1u)) >> 16;
    return (unsigned short)r;
}

// ---------------- Kernel P: cgT[d][k] = bf16(compress[k][d] * (gamma[k]+1)) ----------------
__global__ __launch_bounds__(256) void k_prep(const float* __restrict__ compress,
                                              const float* __restrict__ gamma,
                                              unsigned short* __restrict__ cgT)
{
    __shared__ float tb[64][65];
    __shared__ float gsh[64];
    const int tid = threadIdx.x;
    const int k0 = blockIdx.x * 64;
    #pragma unroll 4
    for (int q = 0; q < 16; ++q) {
        const int idx = q * 256 + tid;
        const int r = idx >> 6, dd = idx & 63;
        tb[r][dd] = compress[(size_t)(k0 + r) * 64 + dd];
    }
    if (tid < 64) gsh[tid] = gamma[k0 + tid] + 1.0f;
    __syncthreads();
    #pragma unroll 4
    for (int q = 0; q < 16; ++q) {
        const int idx = q * 256 + tid;
        const int d = idx >> 6, r = idx & 63;
        cgT[(size_t)d * SD + k0 + r] = f2bf(tb[r][d] * gsh[r]);
    }
}

// ---------------- Kernel PT: tlcatT[n][k] = bf16(tl_cat[k][n]), n in [0,640) ----------------
__global__ __launch_bounds__(256) void k_prept(const float* __restrict__ tl_pre,
                                               const float* __restrict__ tl_al,
                                               const float* __restrict__ tl_nx,
                                               const float* __restrict__ tl_po,
                                               unsigned short* __restrict__ tlT)
{
    const int idx = blockIdx.x * 256 + threadIdx.x;
    if (idx >= 640 * 64) return;
    const int k = idx / 640, n = idx - k * 640;
    float v;
    if (n < 64)       v = tl_pre[k * 64 + n];
    else if (n < 320) v = tl_al[k * 256 + (n - 64)];
    else if (n < 576) v = tl_nx[k * 256 + (n - 320)];
    else              v = tl_po[k * 64 + (n - 576)];
    tlT[(size_t)n * 64 + k] = f2bf(v);
}

// ---------------- Kernel A: codeBF = bf16(rmsnorm-scale * (s @ cg)) via bf16 MFMA ----------------
__global__ __launch_bounds__(256) void k_code3(const float* __restrict__ s,
                                               const unsigned short* __restrict__ cgT,
                                               unsigned short* __restrict__ codeBF)
{
    __shared__ __align__(16) unsigned short s_sh[32 * 152];
    __shared__ __align__(16) unsigned short cg_sh[64 * 152];
    __shared__ float red[4 * 32 * 68];
    __shared__ float ssq_sh[32];
    const int tid  = threadIdx.x;
    const int lane = tid & 63;
    const int wid  = tid >> 6;
    const int tok0 = blockIdx.x * 32;
    const int st_tok = tid >> 3, st_k = (tid & 7) * 16;
    const int sg_d   = tid >> 2, sg_k = (tid & 3) * 32;
    const int wk = wid * 32;

    float ssq = 0.f;
    f32x4 acc[2][4];
    #pragma unroll
    for (int mi = 0; mi < 2; ++mi)
        #pragma unroll
        for (int ni = 0; ni < 4; ++ni) acc[mi][ni] = (f32x4){0.f, 0.f, 0.f, 0.f};

    for (int ks = 0; ks < 32; ++ks) {
        const int kg = ks * 128;
        __syncthreads();
        {
            const float4* sp = (const float4*)(s + (size_t)(tok0 + st_tok) * SD + kg + st_k);
            float4 v0 = sp[0], v1 = sp[1], v2 = sp[2], v3 = sp[3];
            ssq += v0.x*v0.x + v0.y*v0.y + v0.z*v0.z + v0.w*v0.w
                 + v1.x*v1.x + v1.y*v1.y + v1.z*v1.z + v1.w*v1.w
                 + v2.x*v2.x + v2.y*v2.y + v2.z*v2.z + v2.w*v2.w
                 + v3.x*v3.x + v3.y*v3.y + v3.z*v3.z + v3.w*v3.w;
            ushort8 lo, hi;
            lo[0]=f2bf(v0.x); lo[1]=f2bf(v0.y); lo[2]=f2bf(v0.z); lo[3]=f2bf(v0.w);
            lo[4]=f2bf(v1.x); lo[5]=f2bf(v1.y); lo[6]=f2bf(v1.z); lo[7]=f2bf(v1.w);
            hi[0]=f2bf(v2.x); hi[1]=f2bf(v2.y); hi[2]=f2bf(v2.z); hi[3]=f2bf(v2.w);
            hi[4]=f2bf(v3.x); hi[5]=f2bf(v3.y); hi[6]=f2bf(v3.z); hi[7]=f2bf(v3.w);
            ushort8* sw = (ushort8*)(s_sh + st_tok * 152 + st_k);
            sw[0] = lo; sw[1] = hi;
        }
        {
            const ushort8* gp = (const ushort8*)(cgT + (size_t)sg_d * SD + kg + sg_k);
            ushort8 c0 = gp[0], c1 = gp[1], c2 = gp[2], c3 = gp[3];
            ushort8* cw = (ushort8*)(cg_sh + sg_d * 152 + sg_k);
            cw[0] = c0; cw[1] = c1; cw[2] = c2; cw[3] = c3;
        }
        __syncthreads();

        short8 a[2], b[4];
        #pragma unroll
        for (int mi = 0; mi < 2; ++mi)
            a[mi] = *(const short8*)(s_sh + (mi * 16 + (lane & 15)) * 152 + wk + (lane >> 4) * 8);
        #pragma unroll
        for (int ni = 0; ni < 4; ++ni)
            b[ni] = *(const short8*)(cg_sh + (ni * 16 + (lane & 15)) * 152 + wk + (lane >> 4) * 8);
        #pragma unroll
        for (int mi = 0; mi < 2; ++mi)
            #pragma unroll
            for (int ni = 0; ni < 4; ++ni)
                acc[mi][ni] = __builtin_amdgcn_mfma_f32_16x16x32_bf16(a[mi], b[ni], acc[mi][ni], 0, 0, 0);
    }

    ssq += __shfl_xor(ssq, 1);
    ssq += __shfl_xor(ssq, 2);
    ssq += __shfl_xor(ssq, 4);
    if ((tid & 7) == 0) ssq_sh[st_tok] = ssq;

    #pragma unroll
    for (int mi = 0; mi < 2; ++mi)
        #pragma unroll
        for (int ni = 0; ni < 4; ++ni)
            #pragma unroll
            for (int r = 0; r < 4; ++r)
                red[wid * 2176 + (mi * 16 + (lane >> 4) * 4 + r) * 68 + ni * 16 + (lane & 15)] = acc[mi][ni][r];
    __syncthreads();
    if (tid < 32) ssq_sh[tid] = 64.0f / fmaxf(sqrtf(ssq_sh[tid]), 1e-12f);
    __syncthreads();

    #pragma unroll
    for (int q = 0; q < 8; ++q) {
        const int idx = q * 256 + tid;
        const int tok = idx >> 6, d = idx & 63;
        float v = red[0 * 2176 + tok * 68 + d] + red[1 * 2176 + tok * 68 + d]
                + red[2 * 2176 + tok * 68 + d] + red[3 * 2176 + tok * 68 + d];
        codeBF[(size_t)(tok0 + tok) * 64 + d] = f2bf(v * ssq_sh[tok]);
    }
}

// ---------------- Kernel L: logits_all[8192][640] = codeBF @ tlT^T (K=64, MFMA, no LDS) ----------------
__global__ __launch_bounds__(256) void k_logits(const unsigned short* __restrict__ codeBF,
                                                const unsigned short* __restrict__ tlT,
                                                float* __restrict__ logits)
{
    const int tid  = threadIdx.x;
    const int lane = tid & 63;
    const int wid  = tid >> 6;
    const int m0 = blockIdx.y * 64 + wid * 16;   // 16 rows per wave
    const int n0 = blockIdx.x * 128;

    f32x4 acc[8];
    #pragma unroll
    for (int ni = 0; ni < 8; ++ni) acc[ni] = (f32x4){0.f, 0.f, 0.f, 0.f};

    #pragma unroll
    for (int ks = 0; ks < 2; ++ks) {
        const int ko = ks * 32 + (lane >> 4) * 8;
        short8 a = *(const short8*)(codeBF + (size_t)(m0 + (lane & 15)) * 64 + ko);
        short8 b[8];
        #pragma unroll
        for (int ni = 0; ni < 8; ++ni)
            b[ni] = *(const short8*)(tlT + (size_t)(n0 + ni * 16 + (lane & 15)) * 64 + ko);
        #pragma unroll
        for (int ni = 0; ni < 8; ++ni)
            acc[ni] = __builtin_amdgcn_mfma_f32_16x16x32_bf16(a, b[ni], acc[ni], 0, 0, 0);
    }
    #pragma unroll
    for (int ni = 0; ni < 8; ++ni)
        #pragma unroll
        for (int r = 0; r < 4; ++r)
            logits[(size_t)(m0 + (lane >> 4) * 4 + r) * 640 + n0 + ni * 16 + (lane & 15)] = acc[ni][r];
}

// ---------------- linear-domain wave Sinkhorn (algebraically = log-domain reference) ----------------
// Element e = j*64 + lane, (r, c) = (e / COLS, e % COLS). Km = exp(Z).
template <int ROWS, int COLS, int J>
__device__ inline void sinklin(const float* Km, float* P)
{
    const float invR = 1.0f / (float)ROWS;
    const float invC = 1.0f / (float)COLS;
    float u[J];
    float v = 1.0f;
    for (int it = 0; it < ITERS; ++it) {
        float su[J];
        #pragma unroll
        for (int j = 0; j < J; ++j) su[j] = Km[j] * v;
        #pragma unroll
        for (int mask = 1; mask < COLS; mask <<= 1)
            #pragma unroll
            for (int j = 0; j < J; ++j) su[j] += __shfl_xor(su[j], mask);
        #pragma unroll
        for (int j = 0; j < J; ++j) u[j] = invR * __builtin_amdgcn_rcpf(su[j]);
        float sv = 0.f;
        #pragma unroll
        for (int j = 0; j < J; ++j) sv += Km[j] * u[j];
        #pragma unroll
        for (int mask = COLS; mask < 64; mask <<= 1) sv += __shfl_xor(sv, mask);
        v = invC * __builtin_amdgcn_rcpf(sv);
    }
    #pragma unroll
    for (int j = 0; j < J; ++j) P[j] = Km[j] * u[j] * v * (float)ROWS;
}

// ---------------- Kernel B: 4 linear sinkhorns -> P_na/P_np + layer_in(bf16) ----------------
__global__ __launch_bounds__(256) void k_route2(const float* __restrict__ s,
                                                const float* __restrict__ logits,
                                                const float* __restrict__ a_pre_p, const float* __restrict__ H_pre,
                                                const float* __restrict__ a_al_p,  const float* __restrict__ H_al,
                                                const float* __restrict__ a_nx_p,  const float* __restrict__ H_nx,
                                                const float* __restrict__ a_po_p,  const float* __restrict__ H_po,
                                                unsigned short* __restrict__ layer_in,
                                                float* __restrict__ Pna, float* __restrict__ Pnp)
{
    __shared__ float Ppre_sh[64], Pal_sh[256], Pnx_sh[256], Ppo_sh[64];
    const int tid  = threadIdx.x;
    const int lane = tid & 63;
    const int wid  = tid >> 6;
    const int tok  = blockIdx.x;

    // s row in registers (issued early; consumed after barrier)
    float sreg[16];
    #pragma unroll
    for (int j = 0; j < 16; ++j) sreg[j] = s[(size_t)tok * SD + j * 256 + tid];

    const float* lg = logits + (size_t)tok * 640;

    if (wid == 0) {            // pre: 4 x 16
        float Km = expf((*a_pre_p) * lg[lane] + H_pre[lane]);
        float P;
        sinklin<4, 16, 1>(&Km, &P);
        Ppre_sh[lane] = P;
    } else if (wid == 1) {     // align: 16 x 16
        const float aa = *a_al_p;
        float Km[4], P[4];
        #pragma unroll
        for (int j = 0; j < 4; ++j) Km[j] = expf(aa * lg[64 + j * 64 + lane] + H_al[j * 64 + lane]);
        sinklin<16, 16, 4>(Km, P);
        #pragma unroll
        for (int j = 0; j < 4; ++j) Pal_sh[j * 64 + lane] = P[j];
    } else if (wid == 2) {     // next: 16 x 16
        const float aa = *a_nx_p;
        float Km[4], P[4];
        #pragma unroll
        for (int j = 0; j < 4; ++j) Km[j] = expf(aa * lg[320 + j * 64 + lane] + H_nx[j * 64 + lane]);
        sinklin<16, 16, 4>(Km, P);
        #pragma unroll
        for (int j = 0; j < 4; ++j) Pnx_sh[j * 64 + lane] = P[j];
    } else {                   // post: 16 x 4
        float Km = expf((*a_po_p) * lg[576 + lane] + H_po[lane]);
        float P;
        sinklin<16, 4, 1>(&Km, &P);
        Ppo_sh[lane] = P;
    }
    __syncthreads();

    {   // P_na = P_next @ P_align
        const int m = tid >> 4, jj = tid & 15;
        float acc = 0.f;
        #pragma unroll
        for (int t2 = 0; t2 < 16; ++t2) acc += Pnx_sh[m * 16 + t2] * Pal_sh[t2 * 16 + jj];
        Pna[(size_t)tok * 256 + tid] = acc;
    }
    if (tid < 64) {  // P_np = P_next @ P_post
        const int m = tid >> 2, q = tid & 3;
        float acc = 0.f;
        #pragma unroll
        for (int t2 = 0; t2 < 16; ++t2) acc += Pnx_sh[m * 16 + t2] * Ppo_sh[t2 * 4 + q];
        Pnp[(size_t)tok * 64 + tid] = acc;
    }
    {   // layer_in (bf16) from registers
        #pragma unroll
        for (int i = 0; i < 4; ++i) {
            float acc = 0.f;
            #pragma unroll
            for (int j = 0; j < 16; ++j) acc += Ppre_sh[i * 16 + j] * sreg[j];
            layer_in[(size_t)tok * 1024 + i * 256 + tid] = f2bf(acc);
        }
    }
}

// ---------------- Kernel W: transpose + convert W -> WT bf16 [n][k] ----------------
__global__ __launch_bounds__(256) void k_wt(const float* __restrict__ W,
                                            unsigned short* __restrict__ WT)
{
    __shared__ float tb[64][65];
    const int k0 = blockIdx.y * 64, n0 = blockIdx.x * 64;
    #pragma unroll 4
    for (int q = 0; q < 16; ++q) {
        const int idx = q * 256 + threadIdx.x;
        const int r = idx >> 6, c = idx & 63;
        tb[r][c] = W[(size_t)(k0 + r) * 1024 + n0 + c];
    }
    __syncthreads();
    #pragma unroll 4
    for (int q = 0; q < 16; ++q) {
        const int idx = q * 256 + threadIdx.x;
        const int n = idx >> 6, k = idx & 63;
        WT[(size_t)(n0 + n) * 1024 + k0 + k] = f2bf(tb[k][n]);
    }
}

// ---------------- Kernel C: layer_out = layer_in @ WT^T via bf16 MFMA ----------------
__global__ __launch_bounds__(256) void k_gemm_bf16(const unsigned short* __restrict__ A,
                                                   const unsigned short* __restrict__ BT,
                                                   float* __restrict__ C)
{
    __shared__ unsigned short Abuf[128 * 48];
    __shared__ unsigned short Bbuf[128 * 48];
    const int tid  = threadIdx.x;
    const int lane = tid & 63;
    const int wid  = tid >> 6;
    const int wr   = wid >> 1, wc = wid & 1;
    const int m0 = blockIdx.y * 128, n0 = blockIdx.x * 128;

    f32x4 acc[4][4];
    #pragma unroll
    for (int mi = 0; mi < 4; ++mi)
        #pragma unroll
        for (int ni = 0; ni < 4; ++ni) acc[mi][ni] = (f32x4){0.f, 0.f, 0.f, 0.f};

    for (int k0 = 0; k0 < 1024; k0 += 32) {
        __syncthreads();
        #pragma unroll
        for (int h = 0; h < 2; ++h) {
            const int idx = h * 256 + tid;
            const int row = idx >> 2, kq = idx & 3;
            float4 av = *(const float4*)(A + (size_t)(m0 + row) * 1024 + k0 + kq * 8);
            *(float4*)(Abuf + row * 48 + kq * 8) = av;
            float4 bv = *(const float4*)(BT + (size_t)(n0 + row) * 1024 + k0 + kq * 8);
            *(float4*)(Bbuf + row * 48 + kq * 8) = bv;
        }
        __syncthreads();

        short8 a[4], b[4];
        #pragma unroll
        for (int mi = 0; mi < 4; ++mi)
            a[mi] = *(const short8*)(Abuf + (wr * 64 + mi * 16 + (lane & 15)) * 48 + (lane >> 4) * 8);
        #pragma unroll
        for (int ni = 0; ni < 4; ++ni)
            b[ni] = *(const short8*)(Bbuf + (wc * 64 + ni * 16 + (lane & 15)) * 48 + (lane >> 4) * 8);
        #pragma unroll
        for (int mi = 0; mi < 4; ++mi)
            #pragma unroll
            for (int ni = 0; ni < 4; ++ni)
                acc[mi][ni] = __builtin_amdgcn_mfma_f32_16x16x32_bf16(a[mi], b[ni], acc[mi][ni], 0, 0, 0);
    }

    #pragma unroll
    for (int mi = 0; mi < 4; ++mi)
        #pragma unroll
        for (int ni = 0; ni < 4; ++ni)
            #pragma unroll
            for (int r = 0; r < 4; ++r)
                C[(size_t)(m0 + wr * 64 + mi * 16 + (lane >> 4) * 4 + r) * 1024 +
                  n0 + wc * 64 + ni * 16 + (lane & 15)] = acc[mi][ni][r];
}

// ---------------- Kernel D: s_next = P_na @ s + P_np @ layer_out ----------------
__global__ __launch_bounds__(256) void k_final(const float* __restrict__ s,
                                               const float* __restrict__ lo,
                                               const float* __restrict__ Pna,
                                               const float* __restrict__ Pnp,
                                               float* __restrict__ out)
{
    __shared__ float s_sh[SD];
    __shared__ float lo_sh[1024];
    __shared__ float Pna_sh[256];
    __shared__ float Pnp_sh[64];
    const int tid = threadIdx.x;
    const int tok = blockIdx.x;

    {
        const float4* sp4 = (const float4*)(s + (size_t)tok * SD);
        float4* d4 = (float4*)s_sh;
        #pragma unroll
        for (int j = 0; j < 4; ++j) d4[j * 256 + tid] = sp4[j * 256 + tid];
        ((float4*)lo_sh)[tid] = ((const float4*)(lo + (size_t)tok * 1024))[tid];
        Pna_sh[tid] = Pna[(size_t)tok * 256 + tid];
        if (tid < 64) Pnp_sh[tid] = Pnp[(size_t)tok * 64 + tid];
    }
    __syncthreads();

    const int c = tid;
    #pragma unroll
    for (int m = 0; m < 16; ++m) {
        float acc = 0.f;
        #pragma unroll
        for (int j = 0; j < 16; ++j) acc += Pna_sh[m * 16 + j] * s_sh[j * 256 + c];
        #pragma unroll
        for (int q = 0; q < 4; ++q) acc += Pnp_sh[m * 4 + q] * lo_sh[q * 256 + c];
        out[(size_t)tok * SD + m * 256 + c] = acc;
    }
}

extern "C" void kernel_launch(void* const* d_in, const int* in_sizes, int n_in,
                              void* d_out, int out_size, void* d_ws, size_t ws_size,
                              hipStream_t stream)
{
    const float* s        = (const float*)d_in[0];
    const float* gamma    = (const float*)d_in[1];
    const float* compress = (const float*)d_in[2];
    const float* a_pre    = (const float*)d_in[3];
    const float* tl_pre   = (const float*)d_in[4];
    const float* H_pre    = (const float*)d_in[5];
    const float* a_al     = (const float*)d_in[6];
    const float* tl_al    = (const float*)d_in[7];
    const float* H_al     = (const float*)d_in[8];
    const float* a_nx     = (const float*)d_in[9];
    const float* tl_nx    = (const float*)d_in[10];
    const float* H_nx     = (const float*)d_in[11];
    const float* a_po     = (const float*)d_in[12];
    const float* tl_po    = (const float*)d_in[13];
    const float* H_po     = (const float*)d_in[14];
    const float* W        = (const float*)d_in[15];
    float* out = (float*)d_out;

    float* layer_out         = (float*)d_ws;                          // 8192*1024 f32 (aliased as logits 8192*640 pre-GEMM)
    float* logits            = layer_out;
    float* Pna               = layer_out + (size_t)8192 * 1024;       // 8192*256 f32
    float* Pnp               = Pna + (size_t)8192 * 256;              // 8192*64 f32
    unsigned short* layer_in = (unsigned short*)(Pnp + (size_t)8192 * 64);  // 8192*1024 bf16
    unsigned short* WT       = layer_in + (size_t)8192 * 1024;        // 1024*1024 bf16
    unsigned short* cgT      = WT + (size_t)1024 * 1024;              // 64*4096 bf16
    unsigned short* codeBF   = cgT + (size_t)64 * SD;                 // 8192*64 bf16
    unsigned short* tlT      = codeBF + (size_t)8192 * 64;            // 640*64 bf16

    k_wt<<<dim3(16, 16), 256, 0, stream>>>(W, WT);
    k_prep<<<64, 256, 0, stream>>>(compress, gamma, cgT);
    k_prept<<<160, 256, 0, stream>>>(tl_pre, tl_al, tl_nx, tl_po, tlT);
    k_code3<<<256, 256, 0, stream>>>(s, cgT, codeBF);
    k_logits<<<dim3(5, 128), 256, 0, stream>>>(codeBF, tlT, logits);
    k_route2<<<NTOK, 256, 0, stream>>>(s, logits,
                                       a_pre, H_pre, a_al, H_al,
                                       a_nx, H_nx, a_po, H_po,
                                       layer_in, Pna, Pnp);
    k_gemm_bf16<<<dim3(8, 64), 256, 0, stream>>>(layer_in, WT, layer_out);
    k_final<<<NTOK, 256, 0, stream>>>(s, layer_out, Pna, Pnp, out);
}

// Round 5
// 213.661 us; speedup vs baseline: 3.8450x; 1.1669x over previous
//
#include <hip/hip_runtime.h>
#include <math.h>

#define NTOK 8192
#define SD   4096
#define ITERS 20

typedef __attribute__((ext_vector_type(8))) short short8;
typedef __attribute__((ext_vector_type(8))) unsigned short ushort8;
typedef __attribute__((ext_vector_type(4))) float f32x4;

__device__ inline unsigned short f2bf(float x) {
    unsigned int u = __float_as_uint(x);
    unsigned int r = (u + 0x7FFFu + ((u >> 16) & 1u)) >> 16;
    return (unsigned short)r;
}

// ---------------- Kernel P: cgT[d][k] = bf16(compress[k][d] * (gamma[k]+1)) ----------------
__global__ __launch_bounds__(256) void k_prep(const float* __restrict__ compress,
                                              const float* __restrict__ gamma,
                                              unsigned short* __restrict__ cgT)
{
    __shared__ float tb[64][65];
    __shared__ float gsh[64];
    const int tid = threadIdx.x;
    const int k0 = blockIdx.x * 64;
    #pragma unroll 4
    for (int q = 0; q < 16; ++q) {
        const int idx = q * 256 + tid;
        const int r = idx >> 6, dd = idx & 63;
        tb[r][dd] = compress[(size_t)(k0 + r) * 64 + dd];
    }
    if (tid < 64) gsh[tid] = gamma[k0 + tid] + 1.0f;
    __syncthreads();
    #pragma unroll 4
    for (int q = 0; q < 16; ++q) {
        const int idx = q * 256 + tid;
        const int d = idx >> 6, r = idx & 63;
        cgT[(size_t)d * SD + k0 + r] = f2bf(tb[r][d] * gsh[r]);
    }
}

// ---------------- Kernel PT: tlcatT[n][k] = bf16(tl_cat[k][n]), n in [0,640) ----------------
__global__ __launch_bounds__(256) void k_prept(const float* __restrict__ tl_pre,
                                               const float* __restrict__ tl_al,
                                               const float* __restrict__ tl_nx,
                                               const float* __restrict__ tl_po,
                                               unsigned short* __restrict__ tlT)
{
    const int idx = blockIdx.x * 256 + threadIdx.x;
    if (idx >= 640 * 64) return;
    const int k = idx / 640, n = idx - k * 640;
    float v;
    if (n < 64)       v = tl_pre[k * 64 + n];
    else if (n < 320) v = tl_al[k * 256 + (n - 64)];
    else if (n < 576) v = tl_nx[k * 256 + (n - 320)];
    else              v = tl_po[k * 64 + (n - 576)];
    tlT[(size_t)n * 64 + k] = f2bf(v);
}

// ---------------- Kernel A: codeBF = bf16(rmsnorm-scale * (s @ cg)) via bf16 MFMA ----------------
__global__ __launch_bounds__(256) void k_code3(const float* __restrict__ s,
                                               const unsigned short* __restrict__ cgT,
                                               unsigned short* __restrict__ codeBF)
{
    __shared__ __align__(16) unsigned short s_sh[32 * 152];
    __shared__ __align__(16) unsigned short cg_sh[64 * 152];
    __shared__ float red[4 * 32 * 68];
    __shared__ float ssq_sh[32];
    const int tid  = threadIdx.x;
    const int lane = tid & 63;
    const int wid  = tid >> 6;
    const int tok0 = blockIdx.x * 32;
    const int st_tok = tid >> 3, st_k = (tid & 7) * 16;
    const int sg_d   = tid >> 2, sg_k = (tid & 3) * 32;
    const int wk = wid * 32;

    float ssq = 0.f;
    f32x4 acc[2][4];
    #pragma unroll
    for (int mi = 0; mi < 2; ++mi)
        #pragma unroll
        for (int ni = 0; ni < 4; ++ni) acc[mi][ni] = (f32x4){0.f, 0.f, 0.f, 0.f};

    for (int ks = 0; ks < 32; ++ks) {
        const int kg = ks * 128;
        __syncthreads();
        {
            const float4* sp = (const float4*)(s + (size_t)(tok0 + st_tok) * SD + kg + st_k);
            float4 v0 = sp[0], v1 = sp[1], v2 = sp[2], v3 = sp[3];
            ssq += v0.x*v0.x + v0.y*v0.y + v0.z*v0.z + v0.w*v0.w
                 + v1.x*v1.x + v1.y*v1.y + v1.z*v1.z + v1.w*v1.w
                 + v2.x*v2.x + v2.y*v2.y + v2.z*v2.z + v2.w*v2.w
                 + v3.x*v3.x + v3.y*v3.y + v3.z*v3.z + v3.w*v3.w;
            ushort8 lo, hi;
            lo[0]=f2bf(v0.x); lo[1]=f2bf(v0.y); lo[2]=f2bf(v0.z); lo[3]=f2bf(v0.w);
            lo[4]=f2bf(v1.x); lo[5]=f2bf(v1.y); lo[6]=f2bf(v1.z); lo[7]=f2bf(v1.w);
            hi[0]=f2bf(v2.x); hi[1]=f2bf(v2.y); hi[2]=f2bf(v2.z); hi[3]=f2bf(v2.w);
            hi[4]=f2bf(v3.x); hi[5]=f2bf(v3.y); hi[6]=f2bf(v3.z); hi[7]=f2bf(v3.w);
            ushort8* sw = (ushort8*)(s_sh + st_tok * 152 + st_k);
            sw[0] = lo; sw[1] = hi;
        }
        {
            const ushort8* gp = (const ushort8*)(cgT + (size_t)sg_d * SD + kg + sg_k);
            ushort8 c0 = gp[0], c1 = gp[1], c2 = gp[2], c3 = gp[3];
            ushort8* cw = (ushort8*)(cg_sh + sg_d * 152 + sg_k);
            cw[0] = c0; cw[1] = c1; cw[2] = c2; cw[3] = c3;
        }
        __syncthreads();

        short8 a[2], b[4];
        #pragma unroll
        for (int mi = 0; mi < 2; ++mi)
            a[mi] = *(const short8*)(s_sh + (mi * 16 + (lane & 15)) * 152 + wk + (lane >> 4) * 8);
        #pragma unroll
        for (int ni = 0; ni < 4; ++ni)
            b[ni] = *(const short8*)(cg_sh + (ni * 16 + (lane & 15)) * 152 + wk + (lane >> 4) * 8);
        #pragma unroll
        for (int mi = 0; mi < 2; ++mi)
            #pragma unroll
            for (int ni = 0; ni < 4; ++ni)
                acc[mi][ni] = __builtin_amdgcn_mfma_f32_16x16x32_bf16(a[mi], b[ni], acc[mi][ni], 0, 0, 0);
    }

    ssq += __shfl_xor(ssq, 1);
    ssq += __shfl_xor(ssq, 2);
    ssq += __shfl_xor(ssq, 4);
    if ((tid & 7) == 0) ssq_sh[st_tok] = ssq;

    #pragma unroll
    for (int mi = 0; mi < 2; ++mi)
        #pragma unroll
        for (int ni = 0; ni < 4; ++ni)
            #pragma unroll
            for (int r = 0; r < 4; ++r)
                red[wid * 2176 + (mi * 16 + (lane >> 4) * 4 + r) * 68 + ni * 16 + (lane & 15)] = acc[mi][ni][r];
    __syncthreads();
    if (tid < 32) ssq_sh[tid] = 64.0f / fmaxf(sqrtf(ssq_sh[tid]), 1e-12f);
    __syncthreads();

    #pragma unroll
    for (int q = 0; q < 8; ++q) {
        const int idx = q * 256 + tid;
        const int tok = idx >> 6, d = idx & 63;
        float v = red[0 * 2176 + tok * 68 + d] + red[1 * 2176 + tok * 68 + d]
                + red[2 * 2176 + tok * 68 + d] + red[3 * 2176 + tok * 68 + d];
        codeBF[(size_t)(tok0 + tok) * 64 + d] = f2bf(v * ssq_sh[tok]);
    }
}

// ---------------- Kernel L: logits_all[8192][640] = codeBF @ tlT^T (K=64, MFMA, no LDS) ----------------
__global__ __launch_bounds__(256) void k_logits(const unsigned short* __restrict__ codeBF,
                                                const unsigned short* __restrict__ tlT,
                                                float* __restrict__ logits)
{
    const int tid  = threadIdx.x;
    const int lane = tid & 63;
    const int wid  = tid >> 6;
    const int m0 = blockIdx.y * 64 + wid * 16;
    const int n0 = blockIdx.x * 128;

    f32x4 acc[8];
    #pragma unroll
    for (int ni = 0; ni < 8; ++ni) acc[ni] = (f32x4){0.f, 0.f, 0.f, 0.f};

    #pragma unroll
    for (int ks = 0; ks < 2; ++ks) {
        const int ko = ks * 32 + (lane >> 4) * 8;
        short8 a = *(const short8*)(codeBF + (size_t)(m0 + (lane & 15)) * 64 + ko);
        short8 b[8];
        #pragma unroll
        for (int ni = 0; ni < 8; ++ni)
            b[ni] = *(const short8*)(tlT + (size_t)(n0 + ni * 16 + (lane & 15)) * 64 + ko);
        #pragma unroll
        for (int ni = 0; ni < 8; ++ni)
            acc[ni] = __builtin_amdgcn_mfma_f32_16x16x32_bf16(a, b[ni], acc[ni], 0, 0, 0);
    }
    #pragma unroll
    for (int ni = 0; ni < 8; ++ni)
        #pragma unroll
        for (int r = 0; r < 4; ++r)
            logits[(size_t)(m0 + (lane >> 4) * 4 + r) * 640 + n0 + ni * 16 + (lane & 15)] = acc[ni][r];
}

// ---------------- Kernel S: batched linear Sinkhorn (4 lanes/token) + compose ----------------
// Block = 256 thr, 16 tokens. w0: align(16x16) -> Pal_sh; w1: next(16x16) -> Pnx_sh;
// w2: pre(4x16) -> Ppre global; w3: post(16x4) -> Ppo_sh. Then compose Pna/Pnp.
__global__ __launch_bounds__(256) void k_sink(const float* __restrict__ logits,
                                              const float* __restrict__ a_pre_p, const float* __restrict__ H_pre,
                                              const float* __restrict__ a_al_p,  const float* __restrict__ H_al,
                                              const float* __restrict__ a_nx_p,  const float* __restrict__ H_nx,
                                              const float* __restrict__ a_po_p,  const float* __restrict__ H_po,
                                              float* __restrict__ Ppre,
                                              float* __restrict__ Pna, float* __restrict__ Pnp)
{
    __shared__ float Pal_sh[16 * 260];
    __shared__ float Pnx_sh[16 * 260];
    __shared__ float Ppo_sh[16 * 68];
    const int tid  = threadIdx.x;
    const int lane = tid & 63;
    const int wid  = tid >> 6;
    const int tok0 = blockIdx.x * 16;
    const int t_in = lane >> 2;
    const int sub  = lane & 3;
    const int tok  = tok0 + t_in;

    if (wid < 2) {
        // ---- 16x16 Sinkhorn: lane owns rows sub*4..sub*4+3 ----
        const float alpha = (wid == 0) ? (*a_al_p) : (*a_nx_p);
        const float* Hp   = ((wid == 0) ? H_al : H_nx) + sub * 64;
        const float* lgp  = logits + (size_t)tok * 640 + (wid == 0 ? 64 : 320) + sub * 64;
        float Km[4][16];
        #pragma unroll
        for (int rr = 0; rr < 4; ++rr)
            #pragma unroll
            for (int c4 = 0; c4 < 4; ++c4) {
                float4 rv = *(const float4*)(lgp + rr * 16 + c4 * 4);
                float4 hv = *(const float4*)(Hp  + rr * 16 + c4 * 4);
                Km[rr][c4*4+0] = expf(alpha * rv.x + hv.x);
                Km[rr][c4*4+1] = expf(alpha * rv.y + hv.y);
                Km[rr][c4*4+2] = expf(alpha * rv.z + hv.z);
                Km[rr][c4*4+3] = expf(alpha * rv.w + hv.w);
            }
        float v[16], u[4];
        #pragma unroll
        for (int c = 0; c < 16; ++c) v[c] = 1.0f;
        for (int it = 0; it < ITERS; ++it) {
            #pragma unroll
            for (int rr = 0; rr < 4; ++rr) {
                float su = 0.f;
                #pragma unroll
                for (int c = 0; c < 16; ++c) su += Km[rr][c] * v[c];
                u[rr] = 0.0625f * __builtin_amdgcn_rcpf(su);
            }
            float pv[16];
            #pragma unroll
            for (int c = 0; c < 16; ++c)
                pv[c] = Km[0][c]*u[0] + Km[1][c]*u[1] + Km[2][c]*u[2] + Km[3][c]*u[3];
            #pragma unroll
            for (int c = 0; c < 16; ++c) pv[c] += __shfl_xor(pv[c], 1);
            #pragma unroll
            for (int c = 0; c < 16; ++c) pv[c] += __shfl_xor(pv[c], 2);
            #pragma unroll
            for (int c = 0; c < 16; ++c) v[c] = 0.0625f * __builtin_amdgcn_rcpf(pv[c]);
        }
        float* dst = ((wid == 0) ? Pal_sh : Pnx_sh) + t_in * 260;
        #pragma unroll
        for (int rr = 0; rr < 4; ++rr) {
            const float su16 = 16.0f * u[rr];
            #pragma unroll
            for (int c = 0; c < 16; ++c)
                dst[(sub * 4 + rr) * 16 + c] = Km[rr][c] * su16 * v[c];
        }
    } else if (wid == 2) {
        // ---- pre 4x16: lane owns row sub ----
        const float alpha = *a_pre_p;
        const float* lgp = logits + (size_t)tok * 640 + sub * 16;
        const float* Hp  = H_pre + sub * 16;
        float Km[16];
        #pragma unroll
        for (int c4 = 0; c4 < 4; ++c4) {
            float4 rv = *(const float4*)(lgp + c4 * 4);
            float4 hv = *(const float4*)(Hp  + c4 * 4);
            Km[c4*4+0] = expf(alpha * rv.x + hv.x);
            Km[c4*4+1] = expf(alpha * rv.y + hv.y);
            Km[c4*4+2] = expf(alpha * rv.z + hv.z);
            Km[c4*4+3] = expf(alpha * rv.w + hv.w);
        }
        float v[16], u;
        #pragma unroll
        for (int c = 0; c < 16; ++c) v[c] = 1.0f;
        for (int it = 0; it < ITERS; ++it) {
            float su = 0.f;
            #pragma unroll
            for (int c = 0; c < 16; ++c) su += Km[c] * v[c];
            u = 0.25f * __builtin_amdgcn_rcpf(su);
            float pv[16];
            #pragma unroll
            for (int c = 0; c < 16; ++c) pv[c] = Km[c] * u;
            #pragma unroll
            for (int c = 0; c < 16; ++c) pv[c] += __shfl_xor(pv[c], 1);
            #pragma unroll
            for (int c = 0; c < 16; ++c) pv[c] += __shfl_xor(pv[c], 2);
            #pragma unroll
            for (int c = 0; c < 16; ++c) v[c] = 0.0625f * __builtin_amdgcn_rcpf(pv[c]);
        }
        const float su4 = 4.0f * u;
        #pragma unroll
        for (int c = 0; c < 16; ++c)
            Ppre[(size_t)tok * 64 + sub * 16 + c] = Km[c] * su4 * v[c];
    } else {
        // ---- post 16x4: lane owns rows sub*4..sub*4+3 (4 cols) ----
        const float alpha = *a_po_p;
        const float* lgp = logits + (size_t)tok * 640 + 576 + sub * 16;
        const float* Hp  = H_po + sub * 16;
        float Km[4][4];
        #pragma unroll
        for (int rr = 0; rr < 4; ++rr) {
            float4 rv = *(const float4*)(lgp + rr * 4);
            float4 hv = *(const float4*)(Hp  + rr * 4);
            Km[rr][0] = expf(alpha * rv.x + hv.x);
            Km[rr][1] = expf(alpha * rv.y + hv.y);
            Km[rr][2] = expf(alpha * rv.z + hv.z);
            Km[rr][3] = expf(alpha * rv.w + hv.w);
        }
        float v[4], u[4];
        #pragma unroll
        for (int c = 0; c < 4; ++c) v[c] = 1.0f;
        for (int it = 0; it < ITERS; ++it) {
            #pragma unroll
            for (int rr = 0; rr < 4; ++rr) {
                float su = 0.f;
                #pragma unroll
                for (int c = 0; c < 4; ++c) su += Km[rr][c] * v[c];
                u[rr] = 0.0625f * __builtin_amdgcn_rcpf(su);
            }
            float pv[4];
            #pragma unroll
            for (int c = 0; c < 4; ++c)
                pv[c] = Km[0][c]*u[0] + Km[1][c]*u[1] + Km[2][c]*u[2] + Km[3][c]*u[3];
            #pragma unroll
            for (int c = 0; c < 4; ++c) pv[c] += __shfl_xor(pv[c], 1);
            #pragma unroll
            for (int c = 0; c < 4; ++c) pv[c] += __shfl_xor(pv[c], 2);
            #pragma unroll
            for (int c = 0; c < 4; ++c) v[c] = 0.25f * __builtin_amdgcn_rcpf(pv[c]);
        }
        #pragma unroll
        for (int rr = 0; rr < 4; ++rr) {
            const float su16 = 16.0f * u[rr];
            #pragma unroll
            for (int c = 0; c < 4; ++c)
                Ppo_sh[t_in * 68 + (sub * 4 + rr) * 4 + c] = Km[rr][c] * su16 * v[c];
        }
    }
    __syncthreads();

    // ---- compose: Pna = Pnx@Pal, Pnp = Pnx@Ppo ----
    const int ct = tid >> 4;
    const int cj = tid & 15;
    const float* pnx = Pnx_sh + ct * 260;
    const float* pal = Pal_sh + ct * 260;
    const float* ppo = Ppo_sh + ct * 68;
    #pragma unroll
    for (int m = 0; m < 16; ++m) {
        float acc = 0.f;
        #pragma unroll
        for (int t2 = 0; t2 < 16; ++t2) acc += pnx[m * 16 + t2] * pal[t2 * 16 + cj];
        Pna[(size_t)(tok0 + ct) * 256 + m * 16 + cj] = acc;
    }
    #pragma unroll
    for (int e = 0; e < 4; ++e) {
        const int idx = cj * 4 + e;
        const int m = idx >> 2, q = idx & 3;
        float acc = 0.f;
        #pragma unroll
        for (int t2 = 0; t2 < 16; ++t2) acc += pnx[m * 16 + t2] * ppo[t2 * 4 + q];
        Pnp[(size_t)(tok0 + ct) * 64 + idx] = acc;
    }
}

// ---------------- Kernel AP: layer_in = Ppre @ s  (bf16 out) ----------------
__global__ __launch_bounds__(256) void k_apply(const float* __restrict__ s,
                                               const float* __restrict__ Ppre,
                                               unsigned short* __restrict__ layer_in)
{
    __shared__ float Ppre_sh[64];
    const int tid = threadIdx.x;
    const int tok = blockIdx.x;
    float sreg[16];
    #pragma unroll
    for (int j = 0; j < 16; ++j) sreg[j] = s[(size_t)tok * SD + j * 256 + tid];
    if (tid < 64) Ppre_sh[tid] = Ppre[(size_t)tok * 64 + tid];
    __syncthreads();
    #pragma unroll
    for (int i = 0; i < 4; ++i) {
        float acc = 0.f;
        #pragma unroll
        for (int j = 0; j < 16; ++j) acc += Ppre_sh[i * 16 + j] * sreg[j];
        layer_in[(size_t)tok * 1024 + i * 256 + tid] = f2bf(acc);
    }
}

// ---------------- Kernel W: transpose + convert W -> WT bf16 [n][k] ----------------
__global__ __launch_bounds__(256) void k_wt(const float* __restrict__ W,
                                            unsigned short* __restrict__ WT)
{
    __shared__ float tb[64][65];
    const int k0 = blockIdx.y * 64, n0 = blockIdx.x * 64;
    #pragma unroll 4
    for (int q = 0; q < 16; ++q) {
        const int idx = q * 256 + threadIdx.x;
        const int r = idx >> 6, c = idx & 63;
        tb[r][c] = W[(size_t)(k0 + r) * 1024 + n0 + c];
    }
    __syncthreads();
    #pragma unroll 4
    for (int q = 0; q < 16; ++q) {
        const int idx = q * 256 + threadIdx.x;
        const int n = idx >> 6, k = idx & 63;
        WT[(size_t)(n0 + n) * 1024 + k0 + k] = f2bf(tb[k][n]);
    }
}

// ---------------- Kernel C: layer_out = layer_in @ WT^T via bf16 MFMA ----------------
__global__ __launch_bounds__(256) void k_gemm_bf16(const unsigned short* __restrict__ A,
                                                   const unsigned short* __restrict__ BT,
                                                   float* __restrict__ C)
{
    __shared__ unsigned short Abuf[128 * 48];
    __shared__ unsigned short Bbuf[128 * 48];
    const int tid  = threadIdx.x;
    const int lane = tid & 63;
    const int wid  = tid >> 6;
    const int wr   = wid >> 1, wc = wid & 1;
    const int m0 = blockIdx.y * 128, n0 = blockIdx.x * 128;

    f32x4 acc[4][4];
    #pragma unroll
    for (int mi = 0; mi < 4; ++mi)
        #pragma unroll
        for (int ni = 0; ni < 4; ++ni) acc[mi][ni] = (f32x4){0.f, 0.f, 0.f, 0.f};

    for (int k0 = 0; k0 < 1024; k0 += 32) {
        __syncthreads();
        #pragma unroll
        for (int h = 0; h < 2; ++h) {
            const int idx = h * 256 + tid;
            const int row = idx >> 2, kq = idx & 3;
            float4 av = *(const float4*)(A + (size_t)(m0 + row) * 1024 + k0 + kq * 8);
            *(float4*)(Abuf + row * 48 + kq * 8) = av;
            float4 bv = *(const float4*)(BT + (size_t)(n0 + row) * 1024 + k0 + kq * 8);
            *(float4*)(Bbuf + row * 48 + kq * 8) = bv;
        }
        __syncthreads();

        short8 a[4], b[4];
        #pragma unroll
        for (int mi = 0; mi < 4; ++mi)
            a[mi] = *(const short8*)(Abuf + (wr * 64 + mi * 16 + (lane & 15)) * 48 + (lane >> 4) * 8);
        #pragma unroll
        for (int ni = 0; ni < 4; ++ni)
            b[ni] = *(const short8*)(Bbuf + (wc * 64 + ni * 16 + (lane & 15)) * 48 + (lane >> 4) * 8);
        #pragma unroll
        for (int mi = 0; mi < 4; ++mi)
            #pragma unroll
            for (int ni = 0; ni < 4; ++ni)
                acc[mi][ni] = __builtin_amdgcn_mfma_f32_16x16x32_bf16(a[mi], b[ni], acc[mi][ni], 0, 0, 0);
    }

    #pragma unroll
    for (int mi = 0; mi < 4; ++mi)
        #pragma unroll
        for (int ni = 0; ni < 4; ++ni)
            #pragma unroll
            for (int r = 0; r < 4; ++r)
                C[(size_t)(m0 + wr * 64 + mi * 16 + (lane >> 4) * 4 + r) * 1024 +
                  n0 + wc * 64 + ni * 16 + (lane & 15)] = acc[mi][ni][r];
}

// ---------------- Kernel D: s_next = P_na @ s + P_np @ layer_out ----------------
__global__ __launch_bounds__(256) void k_final(const float* __restrict__ s,
                                               const float* __restrict__ lo,
                                               const float* __restrict__ Pna,
                                               const float* __restrict__ Pnp,
                                               float* __restrict__ out)
{
    __shared__ float s_sh[SD];
    __shared__ float lo_sh[1024];
    __shared__ float Pna_sh[256];
    __shared__ float Pnp_sh[64];
    const int tid = threadIdx.x;
    const int tok = blockIdx.x;

    {
        const float4* sp4 = (const float4*)(s + (size_t)tok * SD);
        float4* d4 = (float4*)s_sh;
        #pragma unroll
        for (int j = 0; j < 4; ++j) d4[j * 256 + tid] = sp4[j * 256 + tid];
        ((float4*)lo_sh)[tid] = ((const float4*)(lo + (size_t)tok * 1024))[tid];
        Pna_sh[tid] = Pna[(size_t)tok * 256 + tid];
        if (tid < 64) Pnp_sh[tid] = Pnp[(size_t)tok * 64 + tid];
    }
    __syncthreads();

    const int c = tid;
    #pragma unroll
    for (int m = 0; m < 16; ++m) {
        float acc = 0.f;
        #pragma unroll
        for (int j = 0; j < 16; ++j) acc += Pna_sh[m * 16 + j] * s_sh[j * 256 + c];
        #pragma unroll
        for (int q = 0; q < 4; ++q) acc += Pnp_sh[m * 4 + q] * lo_sh[q * 256 + c];
        out[(size_t)tok * SD + m * 256 + c] = acc;
    }
}

extern "C" void kernel_launch(void* const* d_in, const int* in_sizes, int n_in,
                              void* d_out, int out_size, void* d_ws, size_t ws_size,
                              hipStream_t stream)
{
    const float* s        = (const float*)d_in[0];
    const float* gamma    = (const float*)d_in[1];
    const float* compress = (const float*)d_in[2];
    const float* a_pre    = (const float*)d_in[3];
    const float* tl_pre   = (const float*)d_in[4];
    const float* H_pre    = (const float*)d_in[5];
    const float* a_al     = (const float*)d_in[6];
    const float* tl_al    = (const float*)d_in[7];
    const float* H_al     = (const float*)d_in[8];
    const float* a_nx     = (const float*)d_in[9];
    const float* tl_nx    = (const float*)d_in[10];
    const float* H_nx     = (const float*)d_in[11];
    const float* a_po     = (const float*)d_in[12];
    const float* tl_po    = (const float*)d_in[13];
    const float* H_po     = (const float*)d_in[14];
    const float* W        = (const float*)d_in[15];
    float* out = (float*)d_out;

    float* layer_out         = (float*)d_ws;                          // 8192*1024 f32 (aliased as logits pre-GEMM)
    float* logits            = layer_out;
    float* Pna               = layer_out + (size_t)8192 * 1024;       // 8192*256 f32
    float* Pnp               = Pna + (size_t)8192 * 256;              // 8192*64 f32
    unsigned short* layer_in = (unsigned short*)(Pnp + (size_t)8192 * 64);  // 8192*1024 bf16
    unsigned short* WT       = layer_in + (size_t)8192 * 1024;        // 1024*1024 bf16
    unsigned short* cgT      = WT + (size_t)1024 * 1024;              // 64*4096 bf16
    unsigned short* codeBF   = cgT + (size_t)64 * SD;                 // 8192*64 bf16
    unsigned short* tlT      = codeBF + (size_t)8192 * 64;            // 640*64 bf16
    float* Ppre              = (float*)(tlT + (size_t)640 * 64 + 64); // 8192*64 f32

    k_wt<<<dim3(16, 16), 256, 0, stream>>>(W, WT);
    k_prep<<<64, 256, 0, stream>>>(compress, gamma, cgT);
    k_prept<<<160, 256, 0, stream>>>(tl_pre, tl_al, tl_nx, tl_po, tlT);
    k_code3<<<256, 256, 0, stream>>>(s, cgT, codeBF);
    k_logits<<<dim3(5, 128), 256, 0, stream>>>(codeBF, tlT, logits);
    k_sink<<<512, 256, 0, stream>>>(logits,
                                    a_pre, H_pre, a_al, H_al,
                                    a_nx, H_nx, a_po, H_po,
                                    Ppre, Pna, Pnp);
    k_apply<<<NTOK, 256, 0, stream>>>(s, Ppre, layer_in);
    k_gemm_bf16<<<dim3(8, 64), 256, 0, stream>>>(layer_in, WT, layer_out);
    k_final<<<NTOK, 256, 0, stream>>>(s, layer_out, Pna, Pnp, out);
}